// Round 15
// baseline (657.611 us; speedup 1.0000x reference)
//
#include <hip/hip_runtime.h>

#define N 8192
#define D 1024

typedef short bf16x8 __attribute__((ext_vector_type(8)));
typedef float f32x4 __attribute__((ext_vector_type(4)));
typedef unsigned short u16;

#define WAITV(n) asm volatile("s_waitcnt vmcnt(" #n ")" ::: "memory")
#define BAR() __builtin_amdgcn_s_barrier()
#define SB() __builtin_amdgcn_sched_barrier(0)
#define PRIO(p) __builtin_amdgcn_s_setprio(p)

// Opaque asm load: compiler cannot sink it toward its consumer, so the
// register pipeline actually materializes. vmcnt managed manually.
#define ALOAD(d, p) \
  asm volatile("global_load_dwordx4 %0, %1, off" : "=&v"(d) : "v"(p))

__device__ __forceinline__ u16 f2bf(float f) {
  unsigned u = __float_as_uint(f);
  u += 0x7FFF + ((u >> 16) & 1);   // RNE to bf16
  return (u16)(u >> 16);
}
__device__ __forceinline__ float bf2f(u16 h) {
  return __uint_as_float(((unsigned)h) << 16);
}

__device__ __forceinline__ void gload_lds16(const void* g, const void* l) {
  __builtin_amdgcn_global_load_lds(
      (const __attribute__((address_space(1))) void*)g,
      (__attribute__((address_space(3))) void*)l, 16, 0, 0);
}

// Swizzled [rows][32] bf16 LDS tile (fallback pv staging only).
__device__ __forceinline__ int swz_byte(int row, int logical_chunk) {
  return row * 64 + ((logical_chunk ^ ((row >> 1) & 3)) << 4);
}

// Fragment-major layouts (tile = 16 rows x 32 k, 1 KiB, lane=(r&15)+16*((k>>3)&3)):
//  Xf (qkt): tile (rt, kt) at (rt*32+kt)*2048; hi 1KB then lo 1KB.
//  XTf (pv B): tile (kt, dt) at (kt*64+dt)*1024 (k-major).

// ---------------- K0: split X (fp32) into frag-major hi|lo bf16 ---------
__global__ __launch_bounds__(256) void k_split(const float* __restrict__ X,
                                               u16* __restrict__ Xf) {
  int i = blockIdx.x * 256 + threadIdx.x;   // [0, N*D/8)
  int r = i >> 7;
  int kc = (i & 127) << 3;
  float4 x0 = *(const float4*)(X + (size_t)r * D + kc);
  float4 x1 = *(const float4*)(X + (size_t)r * D + kc + 4);
  float xs[8] = {x0.x, x0.y, x0.z, x0.w, x1.x, x1.y, x1.z, x1.w};
  u16 h[8], lo[8];
#pragma unroll
  for (int j = 0; j < 8; ++j) {
    h[j] = f2bf(xs[j]);
    lo[j] = f2bf(xs[j] - bf2f(h[j]));
  }
  size_t fb = (size_t)((r >> 4) * 32 + (kc >> 5)) * 2048;
  int lbyte = ((r & 15) + ((kc >> 3) & 3) * 16) * 16;
  *(int4*)((char*)Xf + fb + lbyte) = *(int4*)h;
  *(int4*)((char*)Xf + fb + 1024 + lbyte) = *(int4*)lo;
}

// ------ K0b: X (fp32) -> XTf frag-major (FRAG=1) or XT row-major (0) ----
template <int FRAG>
__global__ __launch_bounds__(256) void k_xt(const float* __restrict__ X,
                                            u16* __restrict__ XT) {
  __shared__ u16 t[32][33];
  const int jt = blockIdx.y * 32, dt = blockIdx.x * 32;
  const int c = threadIdx.x & 31, rg = threadIdx.x >> 5;   // rg in 0..7
#pragma unroll
  for (int k = 0; k < 4; ++k) {
    int r = rg * 4 + k;
    t[r][c] = f2bf(X[(size_t)(jt + r) * D + dt + c]);
  }
  __syncthreads();
  if (FRAG) {
    if (threadIdx.x < 128) {
      int dg = dt + (threadIdx.x & 31);
      int jg = jt + (threadIdx.x >> 5) * 8;
      u16 v[8];
#pragma unroll
      for (int e = 0; e < 8; ++e) v[e] = t[(threadIdx.x >> 5) * 8 + e][threadIdx.x & 31];
      size_t tile = (size_t)(jg >> 5) * 64 + (dg >> 4);
      int lane16 = (dg & 15) + 16 * ((jg >> 3) & 3);
      *(int4*)((char*)XT + (tile << 10) + lane16 * 16) = *(int4*)v;
    }
  } else {
#pragma unroll
    for (int k = 0; k < 4; ++k) {
      int d = rg * 4 + k;
      XT[(size_t)(dt + d) * N + jt + c] = t[c][d];
    }
  }
}

// ------- K1: S = X X^T, symmetric upper-tri 128x128 blocks --------------
// Fragment-direct global->VGPR + square-clustered ordering (R13-proven:
// 203 us, FETCH 220 MB, MfmaUtil 47%).
__global__ __launch_bounds__(256) void k_qkt(const u16* __restrict__ Xf,
                                             float* __restrict__ S) {
  __shared__ float tbuf[128][64];   // epilogue transpose bounce only (32 KiB)
  const int tid = threadIdx.x, wid = tid >> 6, lane = tid & 63;

  // XCD chunk swizzle over 2080 blocks (2080 = 8 * 260, bijective)
  int o = blockIdx.x;
  int L = (o & 7) * 260 + (o >> 3);
  // square-clustered mapping: rows of 8x8 squares; row si has one diagonal
  // square (36 tiles) + (7-si) full squares (64 tiles each)
  int si = 0, rem = L;
  while (rem >= 36 + (7 - si) * 64) { rem -= 36 + (7 - si) * 64; ++si; }
  int bi, bj;
  if (rem < 36) {                       // diagonal square (si, si)
    int i = 0;
    while (rem >= 8 - i) { rem -= 8 - i; ++i; }
    bi = si * 8 + i;
    bj = si * 8 + i + rem;
  } else {                              // full square (si, sj), sj > si
    rem -= 36;
    int sj = si + 1 + (rem >> 6);
    int r = rem & 63;
    bi = si * 8 + (r >> 3);
    bj = sj * 8 + (r & 7);
  }
  const int brow = bi * 128, bcol = bj * 128;

  const int wr = wid >> 1, wc = wid & 1;
  const int fr = lane & 15;

  const char* Xfc = (const char*)Xf;
  const char* pA = Xfc + (size_t)(brow / 16 + wr * 4) * 65536 + lane * 16;
  const char* pB = Xfc + (size_t)(bcol / 16 + wc * 4) * 65536 + lane * 16;

  f32x4 acc[4][4] = {};

#define LOADF(P, kt) do {                                                  \
    _Pragma("unroll")                                                      \
    for (int m = 0; m < 4; ++m) {                                          \
      const char* a_ = pA + (size_t)m * 65536 + (size_t)(kt) * 2048;       \
      const char* b_ = pB + (size_t)m * 65536 + (size_t)(kt) * 2048;       \
      P##ah[m] = *(const bf16x8*)a_;                                       \
      P##al[m] = *(const bf16x8*)(a_ + 1024);                              \
      P##bh[m] = *(const bf16x8*)b_;                                       \
      P##bl[m] = *(const bf16x8*)(b_ + 1024);                              \
    }                                                                      \
  } while (0)

#define FMAF(P) do {                                                       \
    PRIO(1);                                                               \
    _Pragma("unroll")                                                      \
    for (int m = 0; m < 4; ++m)                                            \
      _Pragma("unroll")                                                    \
      for (int n = 0; n < 4; ++n) {                                        \
        acc[m][n] = __builtin_amdgcn_mfma_f32_16x16x32_bf16(P##ah[m], P##bh[n], acc[m][n], 0, 0, 0); \
        acc[m][n] = __builtin_amdgcn_mfma_f32_16x16x32_bf16(P##ah[m], P##bl[n], acc[m][n], 0, 0, 0); \
        acc[m][n] = __builtin_amdgcn_mfma_f32_16x16x32_bf16(P##al[m], P##bh[n], acc[m][n], 0, 0, 0); \
      }                                                                    \
    PRIO(0);                                                               \
  } while (0)

  bf16x8 Aah[4], Aal[4], Abh[4], Abl[4];   // buffer A
  bf16x8 Bah[4], Bal[4], Bbh[4], Bbl[4];   // buffer B

  LOADF(A, 0);
  SB();
  for (int kt = 0; kt < 30; kt += 2) {
    LOADF(B, kt + 1);
    SB();
    FMAF(A);
    LOADF(A, kt + 2);
    SB();
    FMAF(B);
  }
  LOADF(B, 31);
  SB();
  FMAF(A);
  FMAF(B);

#undef LOADF
#undef FMAF

  const int rr = (lane >> 4) * 4;
  // direct tile write: S[brow..][bcol..]
#pragma unroll
  for (int m = 0; m < 4; ++m)
#pragma unroll
    for (int n = 0; n < 4; ++n)
#pragma unroll
      for (int r = 0; r < 4; ++r) {
        int row = brow + wr * 64 + m * 16 + rr + r;
        int col = bcol + wc * 64 + n * 16 + fr;
        S[(size_t)row * N + col] = acc[m][n][r];
      }

  // transposed tile write for off-diagonal blocks: S[bcol..][brow..]
  if (bi != bj) {
#pragma unroll
    for (int pass = 0; pass < 2; ++pass) {
      __syncthreads();
      if (wr == pass) {
#pragma unroll
        for (int m = 0; m < 4; ++m)
#pragma unroll
          for (int n = 0; n < 4; ++n) {
            f32x4 v = acc[m][n];
            int c = wc * 64 + n * 16 + fr;
            int inner = ((m * 16 + rr) * 4) ^ ((c & 15) << 4);
            *(f32x4*)((char*)&tbuf[c][0] + inner) = v;
          }
      }
      __syncthreads();
#pragma unroll
      for (int i = 0; i < 8; ++i) {
        int idx = i * 256 + tid;         // 2048 float4 = 128 cols x 16 quads
        int c = idx >> 4;
        int kq = idx & 15;
        int inner = (kq * 16) ^ ((c & 15) << 4);
        float4 v4 = *(const float4*)((const char*)&tbuf[c][0] + inner);
        *(float4*)&S[(size_t)(bcol + c) * N + brow + pass * 64 + kq * 4] = v4;
      }
    }
  }
}

// ---- K2: in-place row softmax (+ optional ROW-MAJOR bf16 P copy) -------
template <int WRITE_PB>
__global__ __launch_bounds__(256) void k_softmax(float* __restrict__ S,
                                                 u16* __restrict__ Pb) {
  const int row = blockIdx.x;
  float* p = S + (size_t)row * N;
  const int tid = threadIdx.x;
  const int wid = tid >> 6, lane = tid & 63;
  __shared__ float red[4];

  float4 v[8];
  float m = -INFINITY;
#pragma unroll
  for (int i = 0; i < 8; ++i) {
    int idx = i * 256 + tid;
    float4 x = ((const float4*)p)[idx];
    if ((row >> 2) == idx) ((float*)&x)[row & 3] = -INFINITY;
    v[i] = x;
    m = fmaxf(m, fmaxf(fmaxf(x.x, x.y), fmaxf(x.z, x.w)));
  }
#pragma unroll
  for (int off = 32; off > 0; off >>= 1) m = fmaxf(m, __shfl_xor(m, off));
  if (lane == 0) red[wid] = m;
  __syncthreads();
  m = fmaxf(fmaxf(red[0], red[1]), fmaxf(red[2], red[3]));

  float s = 0.f;
#pragma unroll
  for (int i = 0; i < 8; ++i) {
    float4 e;
    e.x = __expf(v[i].x - m);
    e.y = __expf(v[i].y - m);
    e.z = __expf(v[i].z - m);
    e.w = __expf(v[i].w - m);
    v[i] = e;
    s += e.x + e.y + e.z + e.w;
  }
#pragma unroll
  for (int off = 32; off > 0; off >>= 1) s += __shfl_xor(s, off);
  __syncthreads();
  if (lane == 0) red[wid] = s;
  __syncthreads();
  s = red[0] + red[1] + red[2] + red[3];
  float inv = 1.0f / s;
#pragma unroll
  for (int i = 0; i < 8; ++i) {
    int idx = i * 256 + tid;
    float4 x = v[i];
    x.x *= inv; x.y *= inv; x.z *= inv; x.w *= inv;
    ((float4*)p)[idx] = x;
    if (WRITE_PB) {
      ushort4 h = {f2bf(x.x), f2bf(x.y), f2bf(x.z), f2bf(x.w)};
      ((ushort4*)(Pb + (size_t)row * N))[idx] = h;
    }
  }
}

// -------- K3: out = P @ X. BM=256, BN=256, 512 thr, wave 128x64 ---------
// Halves L3-level B traffic vs BM=128 (the measured limiter) and doubles
// MFMA per vmem op (32:6). A: row-major Pb via gload_lds, 4 slots, staged
// 3 ahead; B: asm-pinned 2-deep from XTf, issued 2 ahead. WAITV(6) steady.
__global__ __launch_bounds__(512) void k_pv(const u16* __restrict__ Pb,
                                            const u16* __restrict__ XTf,
                                            float* __restrict__ Out) {
  __shared__ u16 As[4][8192];       // 4 slots x 16 KiB (16 frag tiles each)
  const int tid = threadIdx.x, wid = tid >> 6, lane = tid & 63;

  // XCD chunk swizzle over 128 blocks (q=16, bijective): per XCD a
  // 4 brow x 4 bcol square -> Pb and XTf panels maximally shared.
  int o = blockIdx.x;
  int l = (o & 7) * 16 + (o >> 3);
  const int brow = (l >> 2) * 256;
  const int bcol = (l & 3) * 256;

  const int wr = wid >> 2, wc = wid & 3;   // 2x4 waves; wave tile 128x64
  const int fr = lane & 15;

  // B: frag-major XTf base (wave's 4 dt tiles at +0/1024/2048/3072)
  const char* pB = (const char*)XTf + (size_t)(bcol / 16 + wc * 4) * 1024 + lane * 16;

  f32x4 acc[8][4] = {};

#define STAGEA(t) do {                                                     \
    _Pragma("unroll")                                                      \
    for (int c = 0; c < 2; ++c) {                                          \
      int rt = wid * 2 + c;              /* 0..15 frag row-tile */         \
      const u16* src = Pb + (size_t)(brow + rt * 16 + (lane & 15)) * N +   \
                       (size_t)(t) * 32 + (lane >> 4) * 8;                 \
      gload_lds16(src, (const char*)As[(t) & 3] + rt * 1024 + lane * 16);  \
    }                                                                      \
  } while (0)

#define LOADB(BUF, t) do {                                                 \
    const char* b_ = pB + ((size_t)(t) << 16);                             \
    ALOAD(BUF[0], b_);                                                     \
    ALOAD(BUF[1], b_ + 1024);                                              \
    ALOAD(BUF[2], b_ + 2048);                                              \
    ALOAD(BUF[3], b_ + 3072);                                              \
  } while (0)

#define PV_COMPUTE(s, BUF) do {                                            \
    PRIO(1);                                                               \
    _Pragma("unroll")                                                      \
    for (int m = 0; m < 8; ++m) {                                          \
      bf16x8 a = *(const bf16x8*)((const char*)As[s] + (wr * 8 + m) * 1024 + lane * 16); \
      _Pragma("unroll")                                                    \
      for (int n = 0; n < 4; ++n)                                          \
        acc[m][n] = __builtin_amdgcn_mfma_f32_16x16x32_bf16(a, BUF[n], acc[m][n], 0, 0, 0); \
    }                                                                      \
    PRIO(0);                                                               \
  } while (0)

// Steady step: retire tile it's A(2)+B(4) (keep A(it+2)+B(it+1)=6 in
// flight), compute, then issue A(it+3) and B(it+2) into freed slots.
#define STEP(it, BUF) do {                                                 \
    WAITV(6);                                                              \
    SB();                                                                  \
    BAR();                                                                 \
    PV_COMPUTE((it) & 3, BUF);                                             \
    BAR();                                                                 \
    STAGEA((it) + 3);                                                      \
    LOADB(BUF, (it) + 2);                                                  \
    SB();                                                                  \
  } while (0)

  bf16x8 B0[4], B1[4];   // asm-pinned rotation buffers

  STAGEA(0); STAGEA(1); LOADB(B0, 0); STAGEA(2); LOADB(B1, 1);
  SB();

  for (int it = 0; it < 252; it += 2) {
    STEP(it, B0);
    STEP(it + 1, B1);
  }
  // tail: queue = [A253, B252, A254, B253]
  WAITV(6); SB(); BAR();            // retire A253, B252
  PV_COMPUTE(0, B0);                // tile 252
  BAR();
  STAGEA(255); LOADB(B0, 254); SB();  // queue [A254, B253, A255, B254]
  WAITV(6); SB(); BAR();            // retire A254, B253
  PV_COMPUTE(1, B1);                // tile 253
  BAR();
  LOADB(B1, 255); SB();             // queue [A255, B254, B255]
  WAITV(4); SB(); BAR();            // retire A255, B254
  PV_COMPUTE(2, B0);                // tile 254
  BAR();
  WAITV(0); SB(); BAR();
  PV_COMPUTE(3, B1);                // tile 255

#undef STEP
#undef STAGEA
#undef LOADB
#undef PV_COMPUTE

  const int rr = (lane >> 4) * 4;
#pragma unroll
  for (int m = 0; m < 8; ++m)
#pragma unroll
    for (int n = 0; n < 4; ++n)
#pragma unroll
      for (int r = 0; r < 4; ++r) {
        int row = brow + wr * 128 + m * 16 + rr + r;
        int col = bcol + wc * 64 + n * 16 + fr;
        Out[(size_t)row * D + col] = acc[m][n][r];
      }
}

// -------- K3 fallback: out = P @ X from fp32 P (row-major XT) -----------
__global__ __launch_bounds__(512) void k_pv_f32(const float* __restrict__ P,
                                                const u16* __restrict__ XT,
                                                float* __restrict__ Out) {
  __shared__ u16 As[128 * 32];
  __shared__ u16 Bs[256 * 32];
  const int tid = threadIdx.x, wid = tid >> 6, lane = tid & 63;
  const int brow = blockIdx.y * 128;
  const int bcol = blockIdx.x * 256;
  const int wr = wid >> 2, wc = wid & 3;
  const int fr = lane & 15;
  const int c0 = lane >> 4;

  f32x4 acc[4][4] = {};

  for (int kt = 0; kt < N; kt += 32) {
    __syncthreads();
#pragma unroll
    for (int c = 0; c < 2; ++c) {
      int chunk = wid * 2 + c;
      int ebyte = chunk * 1024 + lane * 16;
      int row = ebyte >> 6;
      int pc = (ebyte >> 4) & 3;
      int col = (pc ^ ((row >> 1) & 3)) * 8;
      gload_lds16(XT + (size_t)(bcol + row) * N + kt + col, (const char*)Bs + ebyte);
    }
#pragma unroll
    for (int i = 0; i < 2; ++i) {
      int idx = i * 512 + tid;
      int e = idx * 4;
      int row = e >> 5, col = e & 31;
      float4 x = *(const float4*)(P + (size_t)(brow + row) * N + kt + col);
      ushort4 h = {f2bf(x.x), f2bf(x.y), f2bf(x.z), f2bf(x.w)};
      int inner = (col * 2) ^ (((row >> 1) & 3) << 4);
      *(ushort4*)((char*)As + row * 64 + inner) = h;
    }
    __syncthreads();

    bf16x8 a[4], b[4];
#pragma unroll
    for (int m = 0; m < 4; ++m) {
      int row = wr * 64 + m * 16 + fr;
      a[m] = *(const bf16x8*)((const char*)As + swz_byte(row, c0));
    }
#pragma unroll
    for (int n = 0; n < 4; ++n) {
      int row = wc * 64 + n * 16 + fr;
      b[n] = *(const bf16x8*)((const char*)Bs + swz_byte(row, c0));
    }
#pragma unroll
    for (int m = 0; m < 4; ++m)
#pragma unroll
      for (int n = 0; n < 4; ++n)
        acc[m][n] = __builtin_amdgcn_mfma_f32_16x16x32_bf16(a[m], b[n], acc[m][n], 0, 0, 0);
  }

  const int rr = (lane >> 4) * 4;
#pragma unroll
  for (int m = 0; m < 4; ++m)
#pragma unroll
    for (int n = 0; n < 4; ++n)
#pragma unroll
      for (int r = 0; r < 4; ++r) {
        int row = brow + wr * 64 + m * 16 + rr + r;
        int col = bcol + wc * 64 + n * 16 + fr;
        Out[(size_t)row * D + col] = acc[m][n][r];
      }
}

extern "C" void kernel_launch(void* const* d_in, const int* in_sizes, int n_in,
                              void* d_out, int out_size, void* d_ws, size_t ws_size,
                              hipStream_t stream) {
  const float* X = (const float*)d_in[0];
  float* out = (float*)d_out;
  float* attn = out + (size_t)N * D;        // second output: raw S, then softmaxed

  u16* Xf = (u16*)d_ws;                     // 32 MB (frag-major hi|lo)
  u16* XT = Xf + (size_t)2 * N * D;         // 16 MB (XTf frag-major, or row-major)
  u16* Pb = XT + (size_t)N * D;             // 128 MB (row-major, optional)
  const bool usePb =
      ws_size >= ((size_t)N * D * 3 + (size_t)N * N) * sizeof(u16);

  k_split<<<(N * D / 8) / 256, 256, 0, stream>>>(X, Xf);
  k_qkt<<<64 * 65 / 2, 256, 0, stream>>>(Xf, attn);
  if (usePb) {
    k_xt<1><<<dim3(D / 32, N / 32), 256, 0, stream>>>(X, XT);
    k_softmax<1><<<N, 256, 0, stream>>>(attn, Pb);
    k_pv<<<128, 512, 0, stream>>>(Pb, XT, out);
  } else {
    k_xt<0><<<dim3(D / 32, N / 32), 256, 0, stream>>>(X, XT);
    k_softmax<0><<<N, 256, 0, stream>>>(attn, nullptr);
    k_pv_f32<<<dim3(D / 256, N / 128), 512, 0, stream>>>(attn, XT, out);
  }
}

// Round 16
// 656.399 us; speedup vs baseline: 1.0018x; 1.0018x over previous
//
#include <hip/hip_runtime.h>

#define N 8192
#define D 1024

typedef short bf16x8 __attribute__((ext_vector_type(8)));
typedef float f32x4 __attribute__((ext_vector_type(4)));
typedef unsigned short u16;

#define WAITV(n) asm volatile("s_waitcnt vmcnt(" #n ")" ::: "memory")
#define BAR() __builtin_amdgcn_s_barrier()
#define SB() __builtin_amdgcn_sched_barrier(0)
#define PRIO(p) __builtin_amdgcn_s_setprio(p)

// Opaque asm load: compiler cannot sink it toward its consumer, so the
// register pipeline actually materializes. vmcnt managed manually.
#define ALOAD(d, p) \
  asm volatile("global_load_dwordx4 %0, %1, off" : "=&v"(d) : "v"(p))

__device__ __forceinline__ u16 f2bf(float f) {
  unsigned u = __float_as_uint(f);
  u += 0x7FFF + ((u >> 16) & 1);   // RNE to bf16
  return (u16)(u >> 16);
}
__device__ __forceinline__ float bf2f(u16 h) {
  return __uint_as_float(((unsigned)h) << 16);
}

__device__ __forceinline__ void gload_lds16(const void* g, const void* l) {
  __builtin_amdgcn_global_load_lds(
      (const __attribute__((address_space(1))) void*)g,
      (__attribute__((address_space(3))) void*)l, 16, 0, 0);
}

// Swizzled [rows][32] bf16 LDS tile (fallback pv staging only).
__device__ __forceinline__ int swz_byte(int row, int logical_chunk) {
  return row * 64 + ((logical_chunk ^ ((row >> 1) & 3)) << 4);
}

// Fragment-major layouts (tile = 16 rows x 32 k, 1 KiB, lane=(r&15)+16*((k>>3)&3)):
//  Xf (qkt): tile (rt, kt) at (rt*32+kt)*2048; hi 1KB then lo 1KB.
//  XTf (pv B): tile (kt, dt) at (kt*64+dt)*1024 (k-major).

// ---------------- K0: split X (fp32) into frag-major hi|lo bf16 ---------
__global__ __launch_bounds__(256) void k_split(const float* __restrict__ X,
                                               u16* __restrict__ Xf) {
  int i = blockIdx.x * 256 + threadIdx.x;   // [0, N*D/8)
  int r = i >> 7;
  int kc = (i & 127) << 3;
  float4 x0 = *(const float4*)(X + (size_t)r * D + kc);
  float4 x1 = *(const float4*)(X + (size_t)r * D + kc + 4);
  float xs[8] = {x0.x, x0.y, x0.z, x0.w, x1.x, x1.y, x1.z, x1.w};
  u16 h[8], lo[8];
#pragma unroll
  for (int j = 0; j < 8; ++j) {
    h[j] = f2bf(xs[j]);
    lo[j] = f2bf(xs[j] - bf2f(h[j]));
  }
  size_t fb = (size_t)((r >> 4) * 32 + (kc >> 5)) * 2048;
  int lbyte = ((r & 15) + ((kc >> 3) & 3) * 16) * 16;
  *(int4*)((char*)Xf + fb + lbyte) = *(int4*)h;
  *(int4*)((char*)Xf + fb + 1024 + lbyte) = *(int4*)lo;
}

// ------ K0b: X (fp32) -> XTf frag-major (FRAG=1) or XT row-major (0) ----
template <int FRAG>
__global__ __launch_bounds__(256) void k_xt(const float* __restrict__ X,
                                            u16* __restrict__ XT) {
  __shared__ u16 t[32][33];
  const int jt = blockIdx.y * 32, dt = blockIdx.x * 32;
  const int c = threadIdx.x & 31, rg = threadIdx.x >> 5;   // rg in 0..7
#pragma unroll
  for (int k = 0; k < 4; ++k) {
    int r = rg * 4 + k;
    t[r][c] = f2bf(X[(size_t)(jt + r) * D + dt + c]);
  }
  __syncthreads();
  if (FRAG) {
    if (threadIdx.x < 128) {
      int dg = dt + (threadIdx.x & 31);
      int jg = jt + (threadIdx.x >> 5) * 8;
      u16 v[8];
#pragma unroll
      for (int e = 0; e < 8; ++e) v[e] = t[(threadIdx.x >> 5) * 8 + e][threadIdx.x & 31];
      size_t tile = (size_t)(jg >> 5) * 64 + (dg >> 4);
      int lane16 = (dg & 15) + 16 * ((jg >> 3) & 3);
      *(int4*)((char*)XT + (tile << 10) + lane16 * 16) = *(int4*)v;
    }
  } else {
#pragma unroll
    for (int k = 0; k < 4; ++k) {
      int d = rg * 4 + k;
      XT[(size_t)(dt + d) * N + jt + c] = t[c][d];
    }
  }
}

// ------- K1: S = X X^T, symmetric upper-tri 128x128 blocks --------------
// Fragment-direct global->VGPR + square-clustered ordering (R13-proven:
// 203 us, FETCH 220 MB, MfmaUtil 47%).
__global__ __launch_bounds__(256) void k_qkt(const u16* __restrict__ Xf,
                                             float* __restrict__ S) {
  __shared__ float tbuf[128][64];   // epilogue transpose bounce only (32 KiB)
  const int tid = threadIdx.x, wid = tid >> 6, lane = tid & 63;

  // XCD chunk swizzle over 2080 blocks (2080 = 8 * 260, bijective)
  int o = blockIdx.x;
  int L = (o & 7) * 260 + (o >> 3);
  // square-clustered mapping: rows of 8x8 squares; row si has one diagonal
  // square (36 tiles) + (7-si) full squares (64 tiles each)
  int si = 0, rem = L;
  while (rem >= 36 + (7 - si) * 64) { rem -= 36 + (7 - si) * 64; ++si; }
  int bi, bj;
  if (rem < 36) {                       // diagonal square (si, si)
    int i = 0;
    while (rem >= 8 - i) { rem -= 8 - i; ++i; }
    bi = si * 8 + i;
    bj = si * 8 + i + rem;
  } else {                              // full square (si, sj), sj > si
    rem -= 36;
    int sj = si + 1 + (rem >> 6);
    int r = rem & 63;
    bi = si * 8 + (r >> 3);
    bj = sj * 8 + (r & 7);
  }
  const int brow = bi * 128, bcol = bj * 128;

  const int wr = wid >> 1, wc = wid & 1;
  const int fr = lane & 15;

  const char* Xfc = (const char*)Xf;
  const char* pA = Xfc + (size_t)(brow / 16 + wr * 4) * 65536 + lane * 16;
  const char* pB = Xfc + (size_t)(bcol / 16 + wc * 4) * 65536 + lane * 16;

  f32x4 acc[4][4] = {};

#define LOADF(P, kt) do {                                                  \
    _Pragma("unroll")                                                      \
    for (int m = 0; m < 4; ++m) {                                          \
      const char* a_ = pA + (size_t)m * 65536 + (size_t)(kt) * 2048;       \
      const char* b_ = pB + (size_t)m * 65536 + (size_t)(kt) * 2048;       \
      P##ah[m] = *(const bf16x8*)a_;                                       \
      P##al[m] = *(const bf16x8*)(a_ + 1024);                              \
      P##bh[m] = *(const bf16x8*)b_;                                       \
      P##bl[m] = *(const bf16x8*)(b_ + 1024);                              \
    }                                                                      \
  } while (0)

#define FMAF(P) do {                                                       \
    PRIO(1);                                                               \
    _Pragma("unroll")                                                      \
    for (int m = 0; m < 4; ++m)                                            \
      _Pragma("unroll")                                                    \
      for (int n = 0; n < 4; ++n) {                                        \
        acc[m][n] = __builtin_amdgcn_mfma_f32_16x16x32_bf16(P##ah[m], P##bh[n], acc[m][n], 0, 0, 0); \
        acc[m][n] = __builtin_amdgcn_mfma_f32_16x16x32_bf16(P##ah[m], P##bl[n], acc[m][n], 0, 0, 0); \
        acc[m][n] = __builtin_amdgcn_mfma_f32_16x16x32_bf16(P##al[m], P##bh[n], acc[m][n], 0, 0, 0); \
      }                                                                    \
    PRIO(0);                                                               \
  } while (0)

  bf16x8 Aah[4], Aal[4], Abh[4], Abl[4];   // buffer A
  bf16x8 Bah[4], Bal[4], Bbh[4], Bbl[4];   // buffer B

  LOADF(A, 0);
  SB();
  for (int kt = 0; kt < 30; kt += 2) {
    LOADF(B, kt + 1);
    SB();
    FMAF(A);
    LOADF(A, kt + 2);
    SB();
    FMAF(B);
  }
  LOADF(B, 31);
  SB();
  FMAF(A);
  FMAF(B);

#undef LOADF
#undef FMAF

  const int rr = (lane >> 4) * 4;
  // direct tile write: S[brow..][bcol..]
#pragma unroll
  for (int m = 0; m < 4; ++m)
#pragma unroll
    for (int n = 0; n < 4; ++n)
#pragma unroll
      for (int r = 0; r < 4; ++r) {
        int row = brow + wr * 64 + m * 16 + rr + r;
        int col = bcol + wc * 64 + n * 16 + fr;
        S[(size_t)row * N + col] = acc[m][n][r];
      }

  // transposed tile write for off-diagonal blocks: S[bcol..][brow..]
  if (bi != bj) {
#pragma unroll
    for (int pass = 0; pass < 2; ++pass) {
      __syncthreads();
      if (wr == pass) {
#pragma unroll
        for (int m = 0; m < 4; ++m)
#pragma unroll
          for (int n = 0; n < 4; ++n) {
            f32x4 v = acc[m][n];
            int c = wc * 64 + n * 16 + fr;
            int inner = ((m * 16 + rr) * 4) ^ ((c & 15) << 4);
            *(f32x4*)((char*)&tbuf[c][0] + inner) = v;
          }
      }
      __syncthreads();
#pragma unroll
      for (int i = 0; i < 8; ++i) {
        int idx = i * 256 + tid;         // 2048 float4 = 128 cols x 16 quads
        int c = idx >> 4;
        int kq = idx & 15;
        int inner = (kq * 16) ^ ((c & 15) << 4);
        float4 v4 = *(const float4*)((const char*)&tbuf[c][0] + inner);
        *(float4*)&S[(size_t)(bcol + c) * N + brow + pass * 64 + kq * 4] = v4;
      }
    }
  }
}

// ---- K2: in-place row softmax (+ optional ROW-MAJOR bf16 P copy) -------
template <int WRITE_PB>
__global__ __launch_bounds__(256) void k_softmax(float* __restrict__ S,
                                                 u16* __restrict__ Pb) {
  const int row = blockIdx.x;
  float* p = S + (size_t)row * N;
  const int tid = threadIdx.x;
  const int wid = tid >> 6, lane = tid & 63;
  __shared__ float red[4];

  float4 v[8];
  float m = -INFINITY;
#pragma unroll
  for (int i = 0; i < 8; ++i) {
    int idx = i * 256 + tid;
    float4 x = ((const float4*)p)[idx];
    if ((row >> 2) == idx) ((float*)&x)[row & 3] = -INFINITY;
    v[i] = x;
    m = fmaxf(m, fmaxf(fmaxf(x.x, x.y), fmaxf(x.z, x.w)));
  }
#pragma unroll
  for (int off = 32; off > 0; off >>= 1) m = fmaxf(m, __shfl_xor(m, off));
  if (lane == 0) red[wid] = m;
  __syncthreads();
  m = fmaxf(fmaxf(red[0], red[1]), fmaxf(red[2], red[3]));

  float s = 0.f;
#pragma unroll
  for (int i = 0; i < 8; ++i) {
    float4 e;
    e.x = __expf(v[i].x - m);
    e.y = __expf(v[i].y - m);
    e.z = __expf(v[i].z - m);
    e.w = __expf(v[i].w - m);
    v[i] = e;
    s += e.x + e.y + e.z + e.w;
  }
#pragma unroll
  for (int off = 32; off > 0; off >>= 1) s += __shfl_xor(s, off);
  __syncthreads();
  if (lane == 0) red[wid] = s;
  __syncthreads();
  s = red[0] + red[1] + red[2] + red[3];
  float inv = 1.0f / s;
#pragma unroll
  for (int i = 0; i < 8; ++i) {
    int idx = i * 256 + tid;
    float4 x = v[i];
    x.x *= inv; x.y *= inv; x.z *= inv; x.w *= inv;
    ((float4*)p)[idx] = x;
    if (WRITE_PB) {
      ushort4 h = {f2bf(x.x), f2bf(x.y), f2bf(x.z), f2bf(x.w)};
      ((ushort4*)(Pb + (size_t)row * N))[idx] = h;
    }
  }
}

// -------- K3: out = P @ X. BM=256, BN=256, 512 thr, wave 128x64 ---------
// Halves L3-level B traffic vs BM=128 (the measured limiter) and doubles
// MFMA per vmem op (32:6). A: row-major Pb via gload_lds, 4 slots, staged
// 3 ahead; B: asm-pinned 2-deep from XTf, issued 2 ahead. WAITV(6) steady.
__global__ __launch_bounds__(512) void k_pv(const u16* __restrict__ Pb,
                                            const u16* __restrict__ XTf,
                                            float* __restrict__ Out) {
  __shared__ u16 As[4][8192];       // 4 slots x 16 KiB (16 frag tiles each)
  const int tid = threadIdx.x, wid = tid >> 6, lane = tid & 63;

  // XCD chunk swizzle over 128 blocks (q=16, bijective): per XCD a
  // 4 brow x 4 bcol square -> Pb and XTf panels maximally shared.
  int o = blockIdx.x;
  int l = (o & 7) * 16 + (o >> 3);
  const int brow = (l >> 2) * 256;
  const int bcol = (l & 3) * 256;

  const int wr = wid >> 2, wc = wid & 3;   // 2x4 waves; wave tile 128x64
  const int fr = lane & 15;

  // B: frag-major XTf base (wave's 4 dt tiles at +0/1024/2048/3072)
  const char* pB = (const char*)XTf + (size_t)(bcol / 16 + wc * 4) * 1024 + lane * 16;

  f32x4 acc[8][4] = {};

#define STAGEA(t) do {                                                     \
    _Pragma("unroll")                                                      \
    for (int c = 0; c < 2; ++c) {                                          \
      int rt = wid * 2 + c;              /* 0..15 frag row-tile */         \
      const u16* src = Pb + (size_t)(brow + rt * 16 + (lane & 15)) * N +   \
                       (size_t)(t) * 32 + (lane >> 4) * 8;                 \
      gload_lds16(src, (const char*)As[(t) & 3] + rt * 1024 + lane * 16);  \
    }                                                                      \
  } while (0)

#define LOADB(BUF, t) do {                                                 \
    const char* b_ = pB + ((size_t)(t) << 16);                             \
    ALOAD(BUF[0], b_);                                                     \
    ALOAD(BUF[1], b_ + 1024);                                              \
    ALOAD(BUF[2], b_ + 2048);                                              \
    ALOAD(BUF[3], b_ + 3072);                                              \
  } while (0)

#define PV_COMPUTE(s, BUF) do {                                            \
    PRIO(1);                                                               \
    _Pragma("unroll")                                                      \
    for (int m = 0; m < 8; ++m) {                                          \
      bf16x8 a = *(const bf16x8*)((const char*)As[s] + (wr * 8 + m) * 1024 + lane * 16); \
      _Pragma("unroll")                                                    \
      for (int n = 0; n < 4; ++n)                                          \
        acc[m][n] = __builtin_amdgcn_mfma_f32_16x16x32_bf16(a, BUF[n], acc[m][n], 0, 0, 0); \
    }                                                                      \
    PRIO(0);                                                               \
  } while (0)

// Steady step: retire tile it's A(2)+B(4) (keep A(it+2)+B(it+1)=6 in
// flight), compute, then issue A(it+3) and B(it+2) into freed slots.
#define STEP(it, BUF) do {                                                 \
    WAITV(6);                                                              \
    SB();                                                                  \
    BAR();                                                                 \
    PV_COMPUTE((it) & 3, BUF);                                             \
    BAR();                                                                 \
    STAGEA((it) + 3);                                                      \
    LOADB(BUF, (it) + 2);                                                  \
    SB();                                                                  \
  } while (0)

  bf16x8 B0[4], B1[4];   // asm-pinned rotation buffers

  STAGEA(0); STAGEA(1); LOADB(B0, 0); STAGEA(2); LOADB(B1, 1);
  SB();

  for (int it = 0; it < 252; it += 2) {
    STEP(it, B0);
    STEP(it + 1, B1);
  }
  // tail: queue = [A253, B252, A254, B253]
  WAITV(6); SB(); BAR();            // retire A253, B252
  PV_COMPUTE(0, B0);                // tile 252
  BAR();
  STAGEA(255); LOADB(B0, 254); SB();  // queue [A254, B253, A255, B254]
  WAITV(6); SB(); BAR();            // retire A254, B253
  PV_COMPUTE(1, B1);                // tile 253
  BAR();
  LOADB(B1, 255); SB();             // queue [A255, B254, B255]
  WAITV(4); SB(); BAR();            // retire A255, B254
  PV_COMPUTE(2, B0);                // tile 254
  BAR();
  WAITV(0); SB(); BAR();
  PV_COMPUTE(3, B1);                // tile 255

#undef STEP
#undef STAGEA
#undef LOADB
#undef PV_COMPUTE

  const int rr = (lane >> 4) * 4;
#pragma unroll
  for (int m = 0; m < 8; ++m)
#pragma unroll
    for (int n = 0; n < 4; ++n)
#pragma unroll
      for (int r = 0; r < 4; ++r) {
        int row = brow + wr * 128 + m * 16 + rr + r;
        int col = bcol + wc * 64 + n * 16 + fr;
        Out[(size_t)row * D + col] = acc[m][n][r];
      }
}

// -------- K3 fallback: out = P @ X from fp32 P (row-major XT) -----------
__global__ __launch_bounds__(512) void k_pv_f32(const float* __restrict__ P,
                                                const u16* __restrict__ XT,
                                                float* __restrict__ Out) {
  __shared__ u16 As[128 * 32];
  __shared__ u16 Bs[256 * 32];
  const int tid = threadIdx.x, wid = tid >> 6, lane = tid & 63;
  const int brow = blockIdx.y * 128;
  const int bcol = blockIdx.x * 256;
  const int wr = wid >> 2, wc = wid & 3;
  const int fr = lane & 15;
  const int c0 = lane >> 4;

  f32x4 acc[4][4] = {};

  for (int kt = 0; kt < N; kt += 32) {
    __syncthreads();
#pragma unroll
    for (int c = 0; c < 2; ++c) {
      int chunk = wid * 2 + c;
      int ebyte = chunk * 1024 + lane * 16;
      int row = ebyte >> 6;
      int pc = (ebyte >> 4) & 3;
      int col = (pc ^ ((row >> 1) & 3)) * 8;
      gload_lds16(XT + (size_t)(bcol + row) * N + kt + col, (const char*)Bs + ebyte);
    }
#pragma unroll
    for (int i = 0; i < 2; ++i) {
      int idx = i * 512 + tid;
      int e = idx * 4;
      int row = e >> 5, col = e & 31;
      float4 x = *(const float4*)(P + (size_t)(brow + row) * N + kt + col);
      ushort4 h = {f2bf(x.x), f2bf(x.y), f2bf(x.z), f2bf(x.w)};
      int inner = (col * 2) ^ (((row >> 1) & 3) << 4);
      *(ushort4*)((char*)As + row * 64 + inner) = h;
    }
    __syncthreads();

    bf16x8 a[4], b[4];
#pragma unroll
    for (int m = 0; m < 4; ++m) {
      int row = wr * 64 + m * 16 + fr;
      a[m] = *(const bf16x8*)((const char*)As + swz_byte(row, c0));
    }
#pragma unroll
    for (int n = 0; n < 4; ++n) {
      int row = wc * 64 + n * 16 + fr;
      b[n] = *(const bf16x8*)((const char*)Bs + swz_byte(row, c0));
    }
#pragma unroll
    for (int m = 0; m < 4; ++m)
#pragma unroll
      for (int n = 0; n < 4; ++n)
        acc[m][n] = __builtin_amdgcn_mfma_f32_16x16x32_bf16(a[m], b[n], acc[m][n], 0, 0, 0);
  }

  const int rr = (lane >> 4) * 4;
#pragma unroll
  for (int m = 0; m < 4; ++m)
#pragma unroll
    for (int n = 0; n < 4; ++n)
#pragma unroll
      for (int r = 0; r < 4; ++r) {
        int row = brow + wr * 64 + m * 16 + rr + r;
        int col = bcol + wc * 64 + n * 16 + fr;
        Out[(size_t)row * D + col] = acc[m][n][r];
      }
}

extern "C" void kernel_launch(void* const* d_in, const int* in_sizes, int n_in,
                              void* d_out, int out_size, void* d_ws, size_t ws_size,
                              hipStream_t stream) {
  const float* X = (const float*)d_in[0];
  float* out = (float*)d_out;
  float* attn = out + (size_t)N * D;        // second output: raw S, then softmaxed

  u16* Xf = (u16*)d_ws;                     // 32 MB (frag-major hi|lo)
  u16* XT = Xf + (size_t)2 * N * D;         // 16 MB (XTf frag-major, or row-major)
  u16* Pb = XT + (size_t)N * D;             // 128 MB (row-major, optional)
  const bool usePb =
      ws_size >= ((size_t)N * D * 3 + (size_t)N * N) * sizeof(u16);

  k_split<<<(N * D / 8) / 256, 256, 0, stream>>>(X, Xf);
  k_qkt<<<64 * 65 / 2, 256, 0, stream>>>(Xf, attn);
  if (usePb) {
    k_xt<1><<<dim3(D / 32, N / 32), 256, 0, stream>>>(X, XT);
    k_softmax<1><<<N, 256, 0, stream>>>(attn, Pb);
    k_pv<<<128, 512, 0, stream>>>(Pb, XT, out);
  } else {
    k_xt<0><<<dim3(D / 32, N / 32), 256, 0, stream>>>(X, XT);
    k_softmax<0><<<N, 256, 0, stream>>>(attn, nullptr);
    k_pv_f32<<<dim3(D / 256, N / 128), 512, 0, stream>>>(attn, XT, out);
  }
}

// Round 17
// 578.495 us; speedup vs baseline: 1.1368x; 1.1347x over previous
//
#include <hip/hip_runtime.h>

#define N 8192
#define D 1024

typedef short bf16x8 __attribute__((ext_vector_type(8)));
typedef float f32x4 __attribute__((ext_vector_type(4)));
typedef unsigned short u16;

#define WAITV(n) asm volatile("s_waitcnt vmcnt(" #n ")" ::: "memory")
#define BAR() __builtin_amdgcn_s_barrier()
#define SB() __builtin_amdgcn_sched_barrier(0)
#define PRIO(p) __builtin_amdgcn_s_setprio(p)

// Opaque asm loads: compiler cannot sink them toward consumers or collapse
// the destination lifetimes -> register double-buffer actually materializes.
#define ALOAD(d, p) \
  asm volatile("global_load_dwordx4 %0, %1, off" : "=&v"(d) : "v"(p))
#define ALOAD2(dh, dl, p) \
  asm volatile("global_load_dwordx4 %0, %2, off\n\t" \
               "global_load_dwordx4 %1, %2, off offset:1024" \
               : "=&v"(dh), "=&v"(dl) : "v"(p))

__device__ __forceinline__ u16 f2bf(float f) {
  unsigned u = __float_as_uint(f);
  u += 0x7FFF + ((u >> 16) & 1);   // RNE to bf16
  return (u16)(u >> 16);
}
__device__ __forceinline__ float bf2f(u16 h) {
  return __uint_as_float(((unsigned)h) << 16);
}

__device__ __forceinline__ void gload_lds16(const void* g, const void* l) {
  __builtin_amdgcn_global_load_lds(
      (const __attribute__((address_space(1))) void*)g,
      (__attribute__((address_space(3))) void*)l, 16, 0, 0);
}

// Swizzled [rows][32] bf16 LDS tile (fallback pv staging only).
__device__ __forceinline__ int swz_byte(int row, int logical_chunk) {
  return row * 64 + ((logical_chunk ^ ((row >> 1) & 3)) << 4);
}

// Fragment-major layouts (tile = 16 rows x 32 k, 1 KiB, lane=(r&15)+16*((k>>3)&3)):
//  Xf (qkt): tile (rt, kt) at (rt*32+kt)*2048; hi 1KB then lo 1KB.
//  XTf (pv B): tile (kt, dt) at (kt*64+dt)*1024 (k-major).

// ---------------- K0: split X (fp32) into frag-major hi|lo bf16 ---------
__global__ __launch_bounds__(256) void k_split(const float* __restrict__ X,
                                               u16* __restrict__ Xf) {
  int i = blockIdx.x * 256 + threadIdx.x;   // [0, N*D/8)
  int r = i >> 7;
  int kc = (i & 127) << 3;
  float4 x0 = *(const float4*)(X + (size_t)r * D + kc);
  float4 x1 = *(const float4*)(X + (size_t)r * D + kc + 4);
  float xs[8] = {x0.x, x0.y, x0.z, x0.w, x1.x, x1.y, x1.z, x1.w};
  u16 h[8], lo[8];
#pragma unroll
  for (int j = 0; j < 8; ++j) {
    h[j] = f2bf(xs[j]);
    lo[j] = f2bf(xs[j] - bf2f(h[j]));
  }
  size_t fb = (size_t)((r >> 4) * 32 + (kc >> 5)) * 2048;
  int lbyte = ((r & 15) + ((kc >> 3) & 3) * 16) * 16;
  *(int4*)((char*)Xf + fb + lbyte) = *(int4*)h;
  *(int4*)((char*)Xf + fb + 1024 + lbyte) = *(int4*)lo;
}

// ------ K0b: X (fp32) -> XTf frag-major (FRAG=1) or XT row-major (0) ----
template <int FRAG>
__global__ __launch_bounds__(256) void k_xt(const float* __restrict__ X,
                                            u16* __restrict__ XT) {
  __shared__ u16 t[32][33];
  const int jt = blockIdx.y * 32, dt = blockIdx.x * 32;
  const int c = threadIdx.x & 31, rg = threadIdx.x >> 5;   // rg in 0..7
#pragma unroll
  for (int k = 0; k < 4; ++k) {
    int r = rg * 4 + k;
    t[r][c] = f2bf(X[(size_t)(jt + r) * D + dt + c]);
  }
  __syncthreads();
  if (FRAG) {
    if (threadIdx.x < 128) {
      int dg = dt + (threadIdx.x & 31);
      int jg = jt + (threadIdx.x >> 5) * 8;
      u16 v[8];
#pragma unroll
      for (int e = 0; e < 8; ++e) v[e] = t[(threadIdx.x >> 5) * 8 + e][threadIdx.x & 31];
      size_t tile = (size_t)(jg >> 5) * 64 + (dg >> 4);
      int lane16 = (dg & 15) + 16 * ((jg >> 3) & 3);
      *(int4*)((char*)XT + (tile << 10) + lane16 * 16) = *(int4*)v;
    }
  } else {
#pragma unroll
    for (int k = 0; k < 4; ++k) {
      int d = rg * 4 + k;
      XT[(size_t)(dt + d) * N + jt + c] = t[c][d];
    }
  }
}

// ------- K1: S = X X^T, symmetric upper-tri 128x128 blocks --------------
// Fragment-direct global->VGPR with ASM-PINNED 2-deep register pipeline
// (single change vs the 556-us baseline: real dbuf via ALOAD2 + WAITV(16)).
__global__ __launch_bounds__(256) void k_qkt(const u16* __restrict__ Xf,
                                             float* __restrict__ S) {
  __shared__ float tbuf[128][64];   // epilogue transpose bounce only (32 KiB)
  const int tid = threadIdx.x, wid = tid >> 6, lane = tid & 63;

  // XCD chunk swizzle over 2080 blocks (2080 = 8 * 260, bijective)
  int o = blockIdx.x;
  int l = (o & 7) * 260 + (o >> 3);
  int t = l, bi = 0;
  while (t >= 64 - bi) { t -= 64 - bi; ++bi; }
  const int bj = bi + t;
  const int brow = bi * 128, bcol = bj * 128;

  const int wr = wid >> 1, wc = wid & 1;
  const int fr = lane & 15;

  const char* Xfc = (const char*)Xf;
  const char* pA = Xfc + (size_t)(brow / 16 + wr * 4) * 65536 + lane * 16;
  const char* pB = Xfc + (size_t)(bcol / 16 + wc * 4) * 65536 + lane * 16;

  f32x4 acc[4][4] = {};

#define LOADF(P, kt) do {                                                  \
    _Pragma("unroll")                                                      \
    for (int m = 0; m < 4; ++m) {                                          \
      ALOAD2(P##ah[m], P##al[m], pA + (size_t)m * 65536 + (size_t)(kt) * 2048); \
      ALOAD2(P##bh[m], P##bl[m], pB + (size_t)m * 65536 + (size_t)(kt) * 2048); \
    }                                                                      \
  } while (0)

#define FMAF(P) do {                                                       \
    PRIO(1);                                                               \
    _Pragma("unroll")                                                      \
    for (int m = 0; m < 4; ++m)                                            \
      _Pragma("unroll")                                                    \
      for (int n = 0; n < 4; ++n) {                                        \
        acc[m][n] = __builtin_amdgcn_mfma_f32_16x16x32_bf16(P##ah[m], P##bh[n], acc[m][n], 0, 0, 0); \
        acc[m][n] = __builtin_amdgcn_mfma_f32_16x16x32_bf16(P##ah[m], P##bl[n], acc[m][n], 0, 0, 0); \
        acc[m][n] = __builtin_amdgcn_mfma_f32_16x16x32_bf16(P##al[m], P##bh[n], acc[m][n], 0, 0, 0); \
      }                                                                    \
    PRIO(0);                                                               \
  } while (0)

  bf16x8 Aah[4], Aal[4], Abh[4], Abl[4];   // buffer A (asm-pinned)
  bf16x8 Bah[4], Bal[4], Bbh[4], Bbl[4];   // buffer B (asm-pinned)

  LOADF(A, 0);                     // 16 loads outstanding
  for (int kt = 0; kt < 30; kt += 2) {
    LOADF(B, kt + 1);              // 32 outstanding
    WAITV(16);                     // buffer-A loads complete
    SB();                          // rule #18: fence MFMA below the wait
    FMAF(A);
    LOADF(A, kt + 2);
    WAITV(16);                     // buffer-B loads complete
    SB();
    FMAF(B);
  }
  LOADF(B, 31);
  WAITV(16);
  SB();
  FMAF(A);                         // tile 30
  WAITV(0);
  SB();
  FMAF(B);                         // tile 31

#undef LOADF
#undef FMAF

  const int rr = (lane >> 4) * 4;
  // direct tile write: S[brow..][bcol..]
#pragma unroll
  for (int m = 0; m < 4; ++m)
#pragma unroll
    for (int n = 0; n < 4; ++n)
#pragma unroll
      for (int r = 0; r < 4; ++r) {
        int row = brow + wr * 64 + m * 16 + rr + r;
        int col = bcol + wc * 64 + n * 16 + fr;
        S[(size_t)row * N + col] = acc[m][n][r];
      }

  // transposed tile write for off-diagonal blocks: S[bcol..][brow..]
  if (bi != bj) {
#pragma unroll
    for (int pass = 0; pass < 2; ++pass) {
      __syncthreads();
      if (wr == pass) {
#pragma unroll
        for (int m = 0; m < 4; ++m)
#pragma unroll
          for (int n = 0; n < 4; ++n) {
            f32x4 v = acc[m][n];
            int c = wc * 64 + n * 16 + fr;
            int inner = ((m * 16 + rr) * 4) ^ ((c & 15) << 4);
            *(f32x4*)((char*)&tbuf[c][0] + inner) = v;
          }
      }
      __syncthreads();
#pragma unroll
      for (int i = 0; i < 8; ++i) {
        int idx = i * 256 + tid;         // 2048 float4 = 128 cols x 16 quads
        int c = idx >> 4;
        int kq = idx & 15;
        int inner = (kq * 16) ^ ((c & 15) << 4);
        float4 v4 = *(const float4*)((const char*)&tbuf[c][0] + inner);
        *(float4*)&S[(size_t)(bcol + c) * N + brow + pass * 64 + kq * 4] = v4;
      }
    }
  }
}

// ---- K2: in-place row softmax (+ optional ROW-MAJOR bf16 P copy) -------
template <int WRITE_PB>
__global__ __launch_bounds__(256) void k_softmax(float* __restrict__ S,
                                                 u16* __restrict__ Pb) {
  const int row = blockIdx.x;
  float* p = S + (size_t)row * N;
  const int tid = threadIdx.x;
  const int wid = tid >> 6, lane = tid & 63;
  __shared__ float red[4];

  float4 v[8];
  float m = -INFINITY;
#pragma unroll
  for (int i = 0; i < 8; ++i) {
    int idx = i * 256 + tid;
    float4 x = ((const float4*)p)[idx];
    if ((row >> 2) == idx) ((float*)&x)[row & 3] = -INFINITY;
    v[i] = x;
    m = fmaxf(m, fmaxf(fmaxf(x.x, x.y), fmaxf(x.z, x.w)));
  }
#pragma unroll
  for (int off = 32; off > 0; off >>= 1) m = fmaxf(m, __shfl_xor(m, off));
  if (lane == 0) red[wid] = m;
  __syncthreads();
  m = fmaxf(fmaxf(red[0], red[1]), fmaxf(red[2], red[3]));

  float s = 0.f;
#pragma unroll
  for (int i = 0; i < 8; ++i) {
    float4 e;
    e.x = __expf(v[i].x - m);
    e.y = __expf(v[i].y - m);
    e.z = __expf(v[i].z - m);
    e.w = __expf(v[i].w - m);
    v[i] = e;
    s += e.x + e.y + e.z + e.w;
  }
#pragma unroll
  for (int off = 32; off > 0; off >>= 1) s += __shfl_xor(s, off);
  __syncthreads();
  if (lane == 0) red[wid] = s;
  __syncthreads();
  s = red[0] + red[1] + red[2] + red[3];
  float inv = 1.0f / s;
#pragma unroll
  for (int i = 0; i < 8; ++i) {
    int idx = i * 256 + tid;
    float4 x = v[i];
    x.x *= inv; x.y *= inv; x.z *= inv; x.w *= inv;
    ((float4*)p)[idx] = x;
    if (WRITE_PB) {
      ushort4 h = {f2bf(x.x), f2bf(x.y), f2bf(x.z), f2bf(x.w)};
      ((ushort4*)(Pb + (size_t)row * N))[idx] = h;
    }
  }
}

// -------- K3: out = P @ X. BM=128, BN=256, 512 thr, deep pipeline -------
// (R13-proven best pv: 204 us.) A: Pb via gload_lds into As[4]; B:
// asm-pinned B0/B1/B2 from XTf. 5 vmem/step/wave -> WAITV(10) steady.
__global__ __launch_bounds__(512) void k_pv(const u16* __restrict__ Pb,
                                            const u16* __restrict__ XTf,
                                            float* __restrict__ Out) {
  __shared__ u16 As[4][128 * 32];   // 32 KiB
  const int tid = threadIdx.x, wid = tid >> 6, lane = tid & 63;

  // XCD chunk swizzle over 256 blocks (q=32, bijective)
  int o = blockIdx.x;
  int l = (o & 7) * 32 + (o >> 3);
  const int brow = (l >> 2) * 128;
  const int bcol = (l & 3) * 256;

  const int wr = wid >> 2, wc = wid & 3;   // 2x4 waves, 64x64 each
  const int fr = lane & 15;
  const int c0 = lane >> 4;

  const char* pB = (const char*)XTf + (size_t)(bcol / 16 + wc * 4) * 1024 + lane * 16;

  f32x4 acc[4][4] = {};

#define STAGEA(t) do {                                                     \
    int ebyte = wid * 1024 + lane * 16;                                    \
    int row = ebyte >> 6;                                                  \
    int pc = (ebyte >> 4) & 3;                                             \
    int col = (pc ^ ((row >> 1) & 3)) * 8;                                 \
    gload_lds16(Pb + (size_t)(brow + row) * N + (size_t)(t) * 32 + col,    \
                (const char*)As[(t) & 3] + ebyte);                         \
  } while (0)

#define LOADB(BUF, t) do {                                                 \
    const char* b_ = pB + ((size_t)(t) << 16);                             \
    ALOAD(BUF[0], b_);                                                     \
    ALOAD(BUF[1], b_ + 1024);                                              \
    ALOAD(BUF[2], b_ + 2048);                                              \
    ALOAD(BUF[3], b_ + 3072);                                              \
  } while (0)

#define PV_COMPUTE(s, BUF) do {                                            \
    bf16x8 a[4];                                                           \
    _Pragma("unroll")                                                      \
    for (int m = 0; m < 4; ++m) {                                          \
      int row = wr * 64 + m * 16 + fr;                                     \
      a[m] = *(const bf16x8*)((const char*)As[s] + swz_byte(row, c0));     \
    }                                                                      \
    PRIO(1);                                                               \
    _Pragma("unroll")                                                      \
    for (int m = 0; m < 4; ++m)                                            \
      _Pragma("unroll")                                                    \
      for (int n = 0; n < 4; ++n)                                          \
        acc[m][n] = __builtin_amdgcn_mfma_f32_16x16x32_bf16(a[m], BUF[n], acc[m][n], 0, 0, 0); \
    PRIO(0);                                                               \
  } while (0)

// One steady-state step: retire tile `it`'s 5 loads (10 newer stay in
// flight), compute it, then issue tile it+3 into the just-freed B buffer.
#define STEP(it, BUF) do {                                                 \
    WAITV(10);                                                             \
    SB();                                                                  \
    BAR();                                                                 \
    PV_COMPUTE((it) & 3, BUF);                                             \
    BAR();                                                                 \
    STAGEA((it) + 3);                                                      \
    LOADB(BUF, (it) + 3);                                                  \
    SB();                                                                  \
  } while (0)

  bf16x8 B0[4], B1[4], B2[4];   // asm-pinned rotation buffers

  STAGEA(0); LOADB(B0, 0);
  STAGEA(1); LOADB(B1, 1);
  STAGEA(2); LOADB(B2, 2);      // 15 loads/wave outstanding
  SB();

  for (int t = 0; t < 84; ++t) {   // it = 3t .. 3t+2, covers 0..251
    int it = t * 3;
    STEP(it, B0);
    STEP(it + 1, B1);
    STEP(it + 2, B2);
  }
  STEP(252, B0);                 // issues tile 255 into B0
  // tail: no more issues; drain 10 -> 5 -> 0
  WAITV(10); SB(); BAR();
  PV_COMPUTE(253 & 3, B1);
  BAR();
  WAITV(5); SB(); BAR();
  PV_COMPUTE(254 & 3, B2);
  BAR();
  WAITV(0); SB(); BAR();
  PV_COMPUTE(255 & 3, B0);

#undef STEP
#undef STAGEA
#undef LOADB
#undef PV_COMPUTE

  const int rr = (lane >> 4) * 4;
#pragma unroll
  for (int m = 0; m < 4; ++m)
#pragma unroll
    for (int n = 0; n < 4; ++n)
#pragma unroll
      for (int r = 0; r < 4; ++r) {
        int row = brow + wr * 64 + m * 16 + rr + r;
        int col = bcol + wc * 64 + n * 16 + fr;
        Out[(size_t)row * D + col] = acc[m][n][r];
      }
}

// -------- K3 fallback: out = P @ X from fp32 P (row-major XT) -----------
__global__ __launch_bounds__(512) void k_pv_f32(const float* __restrict__ P,
                                                const u16* __restrict__ XT,
                                                float* __restrict__ Out) {
  __shared__ u16 As[128 * 32];
  __shared__ u16 Bs[256 * 32];
  const int tid = threadIdx.x, wid = tid >> 6, lane = tid & 63;
  const int brow = blockIdx.y * 128;
  const int bcol = blockIdx.x * 256;
  const int wr = wid >> 2, wc = wid & 3;
  const int fr = lane & 15;
  const int c0 = lane >> 4;

  f32x4 acc[4][4] = {};

  for (int kt = 0; kt < N; kt += 32) {
    __syncthreads();
#pragma unroll
    for (int c = 0; c < 2; ++c) {
      int chunk = wid * 2 + c;
      int ebyte = chunk * 1024 + lane * 16;
      int row = ebyte >> 6;
      int pc = (ebyte >> 4) & 3;
      int col = (pc ^ ((row >> 1) & 3)) * 8;
      gload_lds16(XT + (size_t)(bcol + row) * N + kt + col, (const char*)Bs + ebyte);
    }
#pragma unroll
    for (int i = 0; i < 2; ++i) {
      int idx = i * 512 + tid;
      int e = idx * 4;
      int row = e >> 5, col = e & 31;
      float4 x = *(const float4*)(P + (size_t)(brow + row) * N + kt + col);
      ushort4 h = {f2bf(x.x), f2bf(x.y), f2bf(x.z), f2bf(x.w)};
      int inner = (col * 2) ^ (((row >> 1) & 3) << 4);
      *(ushort4*)((char*)As + row * 64 + inner) = h;
    }
    __syncthreads();

    bf16x8 a[4], b[4];
#pragma unroll
    for (int m = 0; m < 4; ++m) {
      int row = wr * 64 + m * 16 + fr;
      a[m] = *(const bf16x8*)((const char*)As + swz_byte(row, c0));
    }
#pragma unroll
    for (int n = 0; n < 4; ++n) {
      int row = wc * 64 + n * 16 + fr;
      b[n] = *(const bf16x8*)((const char*)Bs + swz_byte(row, c0));
    }
#pragma unroll
    for (int m = 0; m < 4; ++m)
#pragma unroll
      for (int n = 0; n < 4; ++n)
        acc[m][n] = __builtin_amdgcn_mfma_f32_16x16x32_bf16(a[m], b[n], acc[m][n], 0, 0, 0);
  }

  const int rr = (lane >> 4) * 4;
#pragma unroll
  for (int m = 0; m < 4; ++m)
#pragma unroll
    for (int n = 0; n < 4; ++n)
#pragma unroll
      for (int r = 0; r < 4; ++r) {
        int row = brow + wr * 64 + m * 16 + rr + r;
        int col = bcol + wc * 64 + n * 16 + fr;
        Out[(size_t)row * D + col] = acc[m][n][r];
      }
}

extern "C" void kernel_launch(void* const* d_in, const int* in_sizes, int n_in,
                              void* d_out, int out_size, void* d_ws, size_t ws_size,
                              hipStream_t stream) {
  const float* X = (const float*)d_in[0];
  float* out = (float*)d_out;
  float* attn = out + (size_t)N * D;        // second output: raw S, then softmaxed

  u16* Xf = (u16*)d_ws;                     // 32 MB (frag-major hi|lo)
  u16* XT = Xf + (size_t)2 * N * D;         // 16 MB (XTf frag-major, or row-major)
  u16* Pb = XT + (size_t)N * D;             // 128 MB (row-major, optional)
  const bool usePb =
      ws_size >= ((size_t)N * D * 3 + (size_t)N * N) * sizeof(u16);

  k_split<<<(N * D / 8) / 256, 256, 0, stream>>>(X, Xf);
  k_qkt<<<64 * 65 / 2, 256, 0, stream>>>(Xf, attn);
  if (usePb) {
    k_xt<1><<<dim3(D / 32, N / 32), 256, 0, stream>>>(X, XT);
    k_softmax<1><<<N, 256, 0, stream>>>(attn, Pb);
    k_pv<<<256, 512, 0, stream>>>(Pb, XT, out);
  } else {
    k_xt<0><<<dim3(D / 32, N / 32), 256, 0, stream>>>(X, XT);
    k_softmax<0><<<N, 256, 0, stream>>>(attn, nullptr);
    k_pv_f32<<<dim3(D / 256, N / 128), 512, 0, stream>>>(attn, XT, out);
  }
}

// Round 18
// 556.589 us; speedup vs baseline: 1.1815x; 1.0394x over previous
//
#include <hip/hip_runtime.h>

#define N 8192
#define D 1024

typedef short bf16x8 __attribute__((ext_vector_type(8)));
typedef float f32x4 __attribute__((ext_vector_type(4)));
typedef unsigned short u16;

#define WAITV(n) asm volatile("s_waitcnt vmcnt(" #n ")" ::: "memory")
#define BAR() __builtin_amdgcn_s_barrier()
#define SB() __builtin_amdgcn_sched_barrier(0)
#define PRIO(p) __builtin_amdgcn_s_setprio(p)

// Opaque asm load: compiler cannot sink it toward its consumer, so the
// register pipeline actually materializes. vmcnt managed manually.
#define ALOAD(d, p) \
  asm volatile("global_load_dwordx4 %0, %1, off" : "=&v"(d) : "v"(p))

__device__ __forceinline__ u16 f2bf(float f) {
  unsigned u = __float_as_uint(f);
  u += 0x7FFF + ((u >> 16) & 1);   // RNE to bf16
  return (u16)(u >> 16);
}
__device__ __forceinline__ float bf2f(u16 h) {
  return __uint_as_float(((unsigned)h) << 16);
}

__device__ __forceinline__ void gload_lds16(const void* g, const void* l) {
  __builtin_amdgcn_global_load_lds(
      (const __attribute__((address_space(1))) void*)g,
      (__attribute__((address_space(3))) void*)l, 16, 0, 0);
}

// Swizzled [rows][32] bf16 LDS tile (pv A-staging): 64 B/row, 4x16B chunks.
__device__ __forceinline__ int swz_byte(int row, int logical_chunk) {
  return row * 64 + ((logical_chunk ^ ((row >> 1) & 3)) << 4);
}

// Fragment-major layouts (tile = 16 rows x 32 k, 1 KiB, lane=(r&15)+16*((k>>3)&3)):
//  Xf (qkt): tile (rt, kt) at (rt*32+kt)*2048; hi 1KB then lo 1KB.
//  XTf (pv B): tile (kt, dt) at (kt*64+dt)*1024 (k-major).

// ---------------- K0: split X (fp32) into frag-major hi|lo bf16 ---------
__global__ __launch_bounds__(256) void k_split(const float* __restrict__ X,
                                               u16* __restrict__ Xf) {
  int i = blockIdx.x * 256 + threadIdx.x;   // [0, N*D/8)
  int r = i >> 7;
  int kc = (i & 127) << 3;
  float4 x0 = *(const float4*)(X + (size_t)r * D + kc);
  float4 x1 = *(const float4*)(X + (size_t)r * D + kc + 4);
  float xs[8] = {x0.x, x0.y, x0.z, x0.w, x1.x, x1.y, x1.z, x1.w};
  u16 h[8], lo[8];
#pragma unroll
  for (int j = 0; j < 8; ++j) {
    h[j] = f2bf(xs[j]);
    lo[j] = f2bf(xs[j] - bf2f(h[j]));
  }
  size_t fb = (size_t)((r >> 4) * 32 + (kc >> 5)) * 2048;
  int lbyte = ((r & 15) + ((kc >> 3) & 3) * 16) * 16;
  *(int4*)((char*)Xf + fb + lbyte) = *(int4*)h;
  *(int4*)((char*)Xf + fb + 1024 + lbyte) = *(int4*)lo;
}

// ------ K0b: X (fp32) -> XTf frag-major (FRAG=1) or XT row-major (0) ----
template <int FRAG>
__global__ __launch_bounds__(256) void k_xt(const float* __restrict__ X,
                                            u16* __restrict__ XT) {
  __shared__ u16 t[32][33];
  const int jt = blockIdx.y * 32, dt = blockIdx.x * 32;
  const int c = threadIdx.x & 31, rg = threadIdx.x >> 5;   // rg in 0..7
#pragma unroll
  for (int k = 0; k < 4; ++k) {
    int r = rg * 4 + k;
    t[r][c] = f2bf(X[(size_t)(jt + r) * D + dt + c]);
  }
  __syncthreads();
  if (FRAG) {
    if (threadIdx.x < 128) {
      int dg = dt + (threadIdx.x & 31);
      int jg = jt + (threadIdx.x >> 5) * 8;
      u16 v[8];
#pragma unroll
      for (int e = 0; e < 8; ++e) v[e] = t[(threadIdx.x >> 5) * 8 + e][threadIdx.x & 31];
      size_t tile = (size_t)(jg >> 5) * 64 + (dg >> 4);
      int lane16 = (dg & 15) + 16 * ((jg >> 3) & 3);
      *(int4*)((char*)XT + (tile << 10) + lane16 * 16) = *(int4*)v;
    }
  } else {
#pragma unroll
    for (int k = 0; k < 4; ++k) {
      int d = rg * 4 + k;
      XT[(size_t)(dt + d) * N + jt + c] = t[c][d];
    }
  }
}

// ------- K1: S = X X^T, symmetric upper-tri 128x128 blocks --------------
// Fragment-direct global->VGPR + square-clustered ordering (R13-proven:
// 203 us, FETCH 220 MB, MfmaUtil 47%).
__global__ __launch_bounds__(256) void k_qkt(const u16* __restrict__ Xf,
                                             float* __restrict__ S) {
  __shared__ float tbuf[128][64];   // epilogue transpose bounce only (32 KiB)
  const int tid = threadIdx.x, wid = tid >> 6, lane = tid & 63;

  // XCD chunk swizzle over 2080 blocks (2080 = 8 * 260, bijective)
  int o = blockIdx.x;
  int L = (o & 7) * 260 + (o >> 3);
  // square-clustered mapping: rows of 8x8 squares; row si has one diagonal
  // square (36 tiles) + (7-si) full squares (64 tiles each)
  int si = 0, rem = L;
  while (rem >= 36 + (7 - si) * 64) { rem -= 36 + (7 - si) * 64; ++si; }
  int bi, bj;
  if (rem < 36) {                       // diagonal square (si, si)
    int i = 0;
    while (rem >= 8 - i) { rem -= 8 - i; ++i; }
    bi = si * 8 + i;
    bj = si * 8 + i + rem;
  } else {                              // full square (si, sj), sj > si
    rem -= 36;
    int sj = si + 1 + (rem >> 6);
    int r = rem & 63;
    bi = si * 8 + (r >> 3);
    bj = sj * 8 + (r & 7);
  }
  const int brow = bi * 128, bcol = bj * 128;

  const int wr = wid >> 1, wc = wid & 1;
  const int fr = lane & 15;

  const char* Xfc = (const char*)Xf;
  const char* pA = Xfc + (size_t)(brow / 16 + wr * 4) * 65536 + lane * 16;
  const char* pB = Xfc + (size_t)(bcol / 16 + wc * 4) * 65536 + lane * 16;

  f32x4 acc[4][4] = {};

#define LOADF(P, kt) do {                                                  \
    _Pragma("unroll")                                                      \
    for (int m = 0; m < 4; ++m) {                                          \
      const char* a_ = pA + (size_t)m * 65536 + (size_t)(kt) * 2048;       \
      const char* b_ = pB + (size_t)m * 65536 + (size_t)(kt) * 2048;       \
      P##ah[m] = *(const bf16x8*)a_;                                       \
      P##al[m] = *(const bf16x8*)(a_ + 1024);                              \
      P##bh[m] = *(const bf16x8*)b_;                                       \
      P##bl[m] = *(const bf16x8*)(b_ + 1024);                              \
    }                                                                      \
  } while (0)

#define FMAF(P) do {                                                       \
    PRIO(1);                                                               \
    _Pragma("unroll")                                                      \
    for (int m = 0; m < 4; ++m)                                            \
      _Pragma("unroll")                                                    \
      for (int n = 0; n < 4; ++n) {                                        \
        acc[m][n] = __builtin_amdgcn_mfma_f32_16x16x32_bf16(P##ah[m], P##bh[n], acc[m][n], 0, 0, 0); \
        acc[m][n] = __builtin_amdgcn_mfma_f32_16x16x32_bf16(P##ah[m], P##bl[n], acc[m][n], 0, 0, 0); \
        acc[m][n] = __builtin_amdgcn_mfma_f32_16x16x32_bf16(P##al[m], P##bh[n], acc[m][n], 0, 0, 0); \
      }                                                                    \
    PRIO(0);                                                               \
  } while (0)

  bf16x8 Aah[4], Aal[4], Abh[4], Abl[4];   // buffer A
  bf16x8 Bah[4], Bal[4], Bbh[4], Bbl[4];   // buffer B

  LOADF(A, 0);
  SB();
  for (int kt = 0; kt < 30; kt += 2) {
    LOADF(B, kt + 1);
    SB();
    FMAF(A);
    LOADF(A, kt + 2);
    SB();
    FMAF(B);
  }
  LOADF(B, 31);
  SB();
  FMAF(A);
  FMAF(B);

#undef LOADF
#undef FMAF

  const int rr = (lane >> 4) * 4;
  // direct tile write: S[brow..][bcol..]
#pragma unroll
  for (int m = 0; m < 4; ++m)
#pragma unroll
    for (int n = 0; n < 4; ++n)
#pragma unroll
      for (int r = 0; r < 4; ++r) {
        int row = brow + wr * 64 + m * 16 + rr + r;
        int col = bcol + wc * 64 + n * 16 + fr;
        S[(size_t)row * N + col] = acc[m][n][r];
      }

  // transposed tile write for off-diagonal blocks: S[bcol..][brow..]
  if (bi != bj) {
#pragma unroll
    for (int pass = 0; pass < 2; ++pass) {
      __syncthreads();
      if (wr == pass) {
#pragma unroll
        for (int m = 0; m < 4; ++m)
#pragma unroll
          for (int n = 0; n < 4; ++n) {
            f32x4 v = acc[m][n];
            int c = wc * 64 + n * 16 + fr;
            int inner = ((m * 16 + rr) * 4) ^ ((c & 15) << 4);
            *(f32x4*)((char*)&tbuf[c][0] + inner) = v;
          }
      }
      __syncthreads();
#pragma unroll
      for (int i = 0; i < 8; ++i) {
        int idx = i * 256 + tid;         // 2048 float4 = 128 cols x 16 quads
        int c = idx >> 4;
        int kq = idx & 15;
        int inner = (kq * 16) ^ ((c & 15) << 4);
        float4 v4 = *(const float4*)((const char*)&tbuf[c][0] + inner);
        *(float4*)&S[(size_t)(bcol + c) * N + brow + pass * 64 + kq * 4] = v4;
      }
    }
  }
}

// ---- K2: in-place row softmax (+ optional ROW-MAJOR bf16 P copy) -------
template <int WRITE_PB>
__global__ __launch_bounds__(256) void k_softmax(float* __restrict__ S,
                                                 u16* __restrict__ Pb) {
  const int row = blockIdx.x;
  float* p = S + (size_t)row * N;
  const int tid = threadIdx.x;
  const int wid = tid >> 6, lane = tid & 63;
  __shared__ float red[4];

  float4 v[8];
  float m = -INFINITY;
#pragma unroll
  for (int i = 0; i < 8; ++i) {
    int idx = i * 256 + tid;
    float4 x = ((const float4*)p)[idx];
    if ((row >> 2) == idx) ((float*)&x)[row & 3] = -INFINITY;
    v[i] = x;
    m = fmaxf(m, fmaxf(fmaxf(x.x, x.y), fmaxf(x.z, x.w)));
  }
#pragma unroll
  for (int off = 32; off > 0; off >>= 1) m = fmaxf(m, __shfl_xor(m, off));
  if (lane == 0) red[wid] = m;
  __syncthreads();
  m = fmaxf(fmaxf(red[0], red[1]), fmaxf(red[2], red[3]));

  float s = 0.f;
#pragma unroll
  for (int i = 0; i < 8; ++i) {
    float4 e;
    e.x = __expf(v[i].x - m);
    e.y = __expf(v[i].y - m);
    e.z = __expf(v[i].z - m);
    e.w = __expf(v[i].w - m);
    v[i] = e;
    s += e.x + e.y + e.z + e.w;
  }
#pragma unroll
  for (int off = 32; off > 0; off >>= 1) s += __shfl_xor(s, off);
  __syncthreads();
  if (lane == 0) red[wid] = s;
  __syncthreads();
  s = red[0] + red[1] + red[2] + red[3];
  float inv = 1.0f / s;
#pragma unroll
  for (int i = 0; i < 8; ++i) {
    int idx = i * 256 + tid;
    float4 x = v[i];
    x.x *= inv; x.y *= inv; x.z *= inv; x.w *= inv;
    ((float4*)p)[idx] = x;
    if (WRITE_PB) {
      ushort4 h = {f2bf(x.x), f2bf(x.y), f2bf(x.z), f2bf(x.w)};
      ((ushort4*)(Pb + (size_t)row * N))[idx] = h;
    }
  }
}

// -------- K3: out = P @ X. BM=128, BN=256, 512 thr, deep pipeline -------
// (R13-proven best pv: 204 us.) A: Pb via gload_lds into As[4]; B:
// asm-pinned B0/B1/B2 from XTf. 5 vmem/step/wave -> WAITV(10) steady.
__global__ __launch_bounds__(512) void k_pv(const u16* __restrict__ Pb,
                                            const u16* __restrict__ XTf,
                                            float* __restrict__ Out) {
  __shared__ u16 As[4][128 * 32];   // 32 KiB
  const int tid = threadIdx.x, wid = tid >> 6, lane = tid & 63;

  // XCD chunk swizzle over 256 blocks (q=32, bijective): per XCD
  // 8 brow x 4 bcol, so Pb panels are shared by the 4 resident bcol-blocks.
  int o = blockIdx.x;
  int l = (o & 7) * 32 + (o >> 3);
  const int brow = (l >> 2) * 128;
  const int bcol = (l & 3) * 256;

  const int wr = wid >> 2, wc = wid & 3;   // 2x4 waves, 64x64 each
  const int fr = lane & 15;
  const int c0 = lane >> 4;

  const char* pB = (const char*)XTf + (size_t)(bcol / 16 + wc * 4) * 1024 + lane * 16;

  f32x4 acc[4][4] = {};

#define STAGEA(t) do {                                                     \
    int ebyte = wid * 1024 + lane * 16;                                    \
    int row = ebyte >> 6;                                                  \
    int pc = (ebyte >> 4) & 3;                                             \
    int col = (pc ^ ((row >> 1) & 3)) * 8;                                 \
    gload_lds16(Pb + (size_t)(brow + row) * N + (size_t)(t) * 32 + col,    \
                (const char*)As[(t) & 3] + ebyte);                         \
  } while (0)

#define LOADB(BUF, t) do {                                                 \
    const char* b_ = pB + ((size_t)(t) << 16);                             \
    ALOAD(BUF[0], b_);                                                     \
    ALOAD(BUF[1], b_ + 1024);                                              \
    ALOAD(BUF[2], b_ + 2048);                                              \
    ALOAD(BUF[3], b_ + 3072);                                              \
  } while (0)

#define PV_COMPUTE(s, BUF) do {                                            \
    bf16x8 a[4];                                                           \
    _Pragma("unroll")                                                      \
    for (int m = 0; m < 4; ++m) {                                          \
      int row = wr * 64 + m * 16 + fr;                                     \
      a[m] = *(const bf16x8*)((const char*)As[s] + swz_byte(row, c0));     \
    }                                                                      \
    PRIO(1);                                                               \
    _Pragma("unroll")                                                      \
    for (int m = 0; m < 4; ++m)                                            \
      _Pragma("unroll")                                                    \
      for (int n = 0; n < 4; ++n)                                          \
        acc[m][n] = __builtin_amdgcn_mfma_f32_16x16x32_bf16(a[m], BUF[n], acc[m][n], 0, 0, 0); \
    PRIO(0);                                                               \
  } while (0)

// One steady-state step: retire tile `it`'s 5 loads (10 newer stay in
// flight), compute it, then issue tile it+3 into the just-freed B buffer.
#define STEP(it, BUF) do {                                                 \
    WAITV(10);                                                             \
    SB();                                                                  \
    BAR();                                                                 \
    PV_COMPUTE((it) & 3, BUF);                                             \
    BAR();                                                                 \
    STAGEA((it) + 3);                                                      \
    LOADB(BUF, (it) + 3);                                                  \
    SB();                                                                  \
  } while (0)

  bf16x8 B0[4], B1[4], B2[4];   // asm-pinned rotation buffers

  STAGEA(0); LOADB(B0, 0);
  STAGEA(1); LOADB(B1, 1);
  STAGEA(2); LOADB(B2, 2);      // 15 loads/wave outstanding
  SB();

  for (int t = 0; t < 84; ++t) {   // it = 3t .. 3t+2, covers 0..251
    int it = t * 3;
    STEP(it, B0);
    STEP(it + 1, B1);
    STEP(it + 2, B2);
  }
  STEP(252, B0);                 // issues tile 255 into B0
  // tail: no more issues; drain 10 -> 5 -> 0
  WAITV(10); SB(); BAR();
  PV_COMPUTE(253 & 3, B1);
  BAR();
  WAITV(5); SB(); BAR();
  PV_COMPUTE(254 & 3, B2);
  BAR();
  WAITV(0); SB(); BAR();
  PV_COMPUTE(255 & 3, B0);

#undef STEP
#undef STAGEA
#undef LOADB
#undef PV_COMPUTE

  const int rr = (lane >> 4) * 4;
#pragma unroll
  for (int m = 0; m < 4; ++m)
#pragma unroll
    for (int n = 0; n < 4; ++n)
#pragma unroll
      for (int r = 0; r < 4; ++r) {
        int row = brow + wr * 64 + m * 16 + rr + r;
        int col = bcol + wc * 64 + n * 16 + fr;
        Out[(size_t)row * D + col] = acc[m][n][r];
      }
}

// -------- K3 fallback: out = P @ X from fp32 P (row-major XT) -----------
__global__ __launch_bounds__(512) void k_pv_f32(const float* __restrict__ P,
                                                const u16* __restrict__ XT,
                                                float* __restrict__ Out) {
  __shared__ u16 As[128 * 32];
  __shared__ u16 Bs[256 * 32];
  const int tid = threadIdx.x, wid = tid >> 6, lane = tid & 63;
  const int brow = blockIdx.y * 128;
  const int bcol = blockIdx.x * 256;
  const int wr = wid >> 2, wc = wid & 3;
  const int fr = lane & 15;
  const int c0 = lane >> 4;

  f32x4 acc[4][4] = {};

  for (int kt = 0; kt < N; kt += 32) {
    __syncthreads();
#pragma unroll
    for (int c = 0; c < 2; ++c) {
      int chunk = wid * 2 + c;
      int ebyte = chunk * 1024 + lane * 16;
      int row = ebyte >> 6;
      int pc = (ebyte >> 4) & 3;
      int col = (pc ^ ((row >> 1) & 3)) * 8;
      gload_lds16(XT + (size_t)(bcol + row) * N + kt + col, (const char*)Bs + ebyte);
    }
#pragma unroll
    for (int i = 0; i < 2; ++i) {
      int idx = i * 512 + tid;
      int e = idx * 4;
      int row = e >> 5, col = e & 31;
      float4 x = *(const float4*)(P + (size_t)(brow + row) * N + kt + col);
      ushort4 h = {f2bf(x.x), f2bf(x.y), f2bf(x.z), f2bf(x.w)};
      int inner = (col * 2) ^ (((row >> 1) & 3) << 4);
      *(ushort4*)((char*)As + row * 64 + inner) = h;
    }
    __syncthreads();

    bf16x8 a[4], b[4];
#pragma unroll
    for (int m = 0; m < 4; ++m) {
      int row = wr * 64 + m * 16 + fr;
      a[m] = *(const bf16x8*)((const char*)As + swz_byte(row, c0));
    }
#pragma unroll
    for (int n = 0; n < 4; ++n) {
      int row = wc * 64 + n * 16 + fr;
      b[n] = *(const bf16x8*)((const char*)Bs + swz_byte(row, c0));
    }
#pragma unroll
    for (int m = 0; m < 4; ++m)
#pragma unroll
      for (int n = 0; n < 4; ++n)
        acc[m][n] = __builtin_amdgcn_mfma_f32_16x16x32_bf16(a[m], b[n], acc[m][n], 0, 0, 0);
  }

  const int rr = (lane >> 4) * 4;
#pragma unroll
  for (int m = 0; m < 4; ++m)
#pragma unroll
    for (int n = 0; n < 4; ++n)
#pragma unroll
      for (int r = 0; r < 4; ++r) {
        int row = brow + wr * 64 + m * 16 + rr + r;
        int col = bcol + wc * 64 + n * 16 + fr;
        Out[(size_t)row * D + col] = acc[m][n][r];
      }
}

extern "C" void kernel_launch(void* const* d_in, const int* in_sizes, int n_in,
                              void* d_out, int out_size, void* d_ws, size_t ws_size,
                              hipStream_t stream) {
  const float* X = (const float*)d_in[0];
  float* out = (float*)d_out;
  float* attn = out + (size_t)N * D;        // second output: raw S, then softmaxed

  u16* Xf = (u16*)d_ws;                     // 32 MB (frag-major hi|lo)
  u16* XT = Xf + (size_t)2 * N * D;         // 16 MB (XTf frag-major, or row-major)
  u16* Pb = XT + (size_t)N * D;             // 128 MB (row-major, optional)
  const bool usePb =
      ws_size >= ((size_t)N * D * 3 + (size_t)N * N) * sizeof(u16);

  k_split<<<(N * D / 8) / 256, 256, 0, stream>>>(X, Xf);
  k_qkt<<<64 * 65 / 2, 256, 0, stream>>>(Xf, attn);
  if (usePb) {
    k_xt<1><<<dim3(D / 32, N / 32), 256, 0, stream>>>(X, XT);
    k_softmax<1><<<N, 256, 0, stream>>>(attn, Pb);
    k_pv<<<256, 512, 0, stream>>>(Pb, XT, out);
  } else {
    k_xt<0><<<dim3(D / 32, N / 32), 256, 0, stream>>>(X, XT);
    k_softmax<0><<<N, 256, 0, stream>>>(attn, nullptr);
    k_pv_f32<<<dim3(D / 256, N / 128), 512, 0, stream>>>(attn, XT, out);
  }
}

// Round 19
// 464.075 us; speedup vs baseline: 1.4170x; 1.1994x over previous
//
#include <hip/hip_runtime.h>

#define N 8192
#define D 1024

typedef short bf16x8 __attribute__((ext_vector_type(8)));
typedef float f32x4 __attribute__((ext_vector_type(4)));
typedef unsigned short u16;

#define WAITV(n) asm volatile("s_waitcnt vmcnt(" #n ")" ::: "memory")
#define BAR() __builtin_amdgcn_s_barrier()
#define SB() __builtin_amdgcn_sched_barrier(0)
#define PRIO(p) __builtin_amdgcn_s_setprio(p)

// Opaque asm load: compiler cannot sink it toward its consumer, so the
// register pipeline actually materializes. vmcnt managed manually.
#define ALOAD(d, p) \
  asm volatile("global_load_dwordx4 %0, %1, off" : "=&v"(d) : "v"(p))

__device__ __forceinline__ u16 f2bf(float f) {
  unsigned u = __float_as_uint(f);
  u += 0x7FFF + ((u >> 16) & 1);   // RNE to bf16
  return (u16)(u >> 16);
}
__device__ __forceinline__ float bf2f(u16 h) {
  return __uint_as_float(((unsigned)h) << 16);
}

__device__ __forceinline__ void gload_lds16(const void* g, const void* l) {
  __builtin_amdgcn_global_load_lds(
      (const __attribute__((address_space(1))) void*)g,
      (__attribute__((address_space(3))) void*)l, 16, 0, 0);
}

// Swizzled [rows][32] bf16 LDS tile (pv A-staging): 64 B/row, 4x16B chunks.
__device__ __forceinline__ int swz_byte(int row, int logical_chunk) {
  return row * 64 + ((logical_chunk ^ ((row >> 1) & 3)) << 4);
}

// Fragment-major layouts (tile = 16 rows x 32 k, 1 KiB, lane=(r&15)+16*((k>>3)&3)):
//  Xf (qkt): tile (rt, kt) at (rt*32+kt)*2048; hi 1KB then lo 1KB.
//  XTf (pv B): tile (kt, dt) at (kt*64+dt)*1024 (k-major).

// ---------------- K0: split X (fp32) into frag-major hi|lo bf16 ---------
__global__ __launch_bounds__(256) void k_split(const float* __restrict__ X,
                                               u16* __restrict__ Xf) {
  int i = blockIdx.x * 256 + threadIdx.x;   // [0, N*D/8)
  int r = i >> 7;
  int kc = (i & 127) << 3;
  float4 x0 = *(const float4*)(X + (size_t)r * D + kc);
  float4 x1 = *(const float4*)(X + (size_t)r * D + kc + 4);
  float xs[8] = {x0.x, x0.y, x0.z, x0.w, x1.x, x1.y, x1.z, x1.w};
  u16 h[8], lo[8];
#pragma unroll
  for (int j = 0; j < 8; ++j) {
    h[j] = f2bf(xs[j]);
    lo[j] = f2bf(xs[j] - bf2f(h[j]));
  }
  size_t fb = (size_t)((r >> 4) * 32 + (kc >> 5)) * 2048;
  int lbyte = ((r & 15) + ((kc >> 3) & 3) * 16) * 16;
  *(int4*)((char*)Xf + fb + lbyte) = *(int4*)h;
  *(int4*)((char*)Xf + fb + 1024 + lbyte) = *(int4*)lo;
}

// ------ K0b: X (fp32) -> XTf frag-major (FRAG=1) or XT row-major (0) ----
template <int FRAG>
__global__ __launch_bounds__(256) void k_xt(const float* __restrict__ X,
                                            u16* __restrict__ XT) {
  __shared__ u16 t[32][33];
  const int jt = blockIdx.y * 32, dt = blockIdx.x * 32;
  const int c = threadIdx.x & 31, rg = threadIdx.x >> 5;   // rg in 0..7
#pragma unroll
  for (int k = 0; k < 4; ++k) {
    int r = rg * 4 + k;
    t[r][c] = f2bf(X[(size_t)(jt + r) * D + dt + c]);
  }
  __syncthreads();
  if (FRAG) {
    if (threadIdx.x < 128) {
      int dg = dt + (threadIdx.x & 31);
      int jg = jt + (threadIdx.x >> 5) * 8;
      u16 v[8];
#pragma unroll
      for (int e = 0; e < 8; ++e) v[e] = t[(threadIdx.x >> 5) * 8 + e][threadIdx.x & 31];
      size_t tile = (size_t)(jg >> 5) * 64 + (dg >> 4);
      int lane16 = (dg & 15) + 16 * ((jg >> 3) & 3);
      *(int4*)((char*)XT + (tile << 10) + lane16 * 16) = *(int4*)v;
    }
  } else {
#pragma unroll
    for (int k = 0; k < 4; ++k) {
      int d = rg * 4 + k;
      XT[(size_t)(dt + d) * N + jt + c] = t[c][d];
    }
  }
}

// ------- K1: S = X X^T, symmetric upper-tri 128x128 blocks --------------
// Fragment-direct global->VGPR + square-clustered ordering (R13-proven).
// NEW: non-temporal S stores -> the 262 MB output stream no longer evicts
// the 32 MB Xf from L3 (measured FETCH was 220 MB vs 32 MB input).
__global__ __launch_bounds__(256) void k_qkt(const u16* __restrict__ Xf,
                                             float* __restrict__ S) {
  __shared__ float tbuf[128][64];   // epilogue transpose bounce only (32 KiB)
  const int tid = threadIdx.x, wid = tid >> 6, lane = tid & 63;

  // XCD chunk swizzle over 2080 blocks (2080 = 8 * 260, bijective)
  int o = blockIdx.x;
  int L = (o & 7) * 260 + (o >> 3);
  // square-clustered mapping: rows of 8x8 squares; row si has one diagonal
  // square (36 tiles) + (7-si) full squares (64 tiles each)
  int si = 0, rem = L;
  while (rem >= 36 + (7 - si) * 64) { rem -= 36 + (7 - si) * 64; ++si; }
  int bi, bj;
  if (rem < 36) {                       // diagonal square (si, si)
    int i = 0;
    while (rem >= 8 - i) { rem -= 8 - i; ++i; }
    bi = si * 8 + i;
    bj = si * 8 + i + rem;
  } else {                              // full square (si, sj), sj > si
    rem -= 36;
    int sj = si + 1 + (rem >> 6);
    int r = rem & 63;
    bi = si * 8 + (r >> 3);
    bj = sj * 8 + (r & 7);
  }
  const int brow = bi * 128, bcol = bj * 128;

  const int wr = wid >> 1, wc = wid & 1;
  const int fr = lane & 15;

  const char* Xfc = (const char*)Xf;
  const char* pA = Xfc + (size_t)(brow / 16 + wr * 4) * 65536 + lane * 16;
  const char* pB = Xfc + (size_t)(bcol / 16 + wc * 4) * 65536 + lane * 16;

  f32x4 acc[4][4] = {};

#define LOADF(P, kt) do {                                                  \
    _Pragma("unroll")                                                      \
    for (int m = 0; m < 4; ++m) {                                          \
      const char* a_ = pA + (size_t)m * 65536 + (size_t)(kt) * 2048;       \
      const char* b_ = pB + (size_t)m * 65536 + (size_t)(kt) * 2048;       \
      P##ah[m] = *(const bf16x8*)a_;                                       \
      P##al[m] = *(const bf16x8*)(a_ + 1024);                              \
      P##bh[m] = *(const bf16x8*)b_;                                       \
      P##bl[m] = *(const bf16x8*)(b_ + 1024);                              \
    }                                                                      \
  } while (0)

#define FMAF(P) do {                                                       \
    PRIO(1);                                                               \
    _Pragma("unroll")                                                      \
    for (int m = 0; m < 4; ++m)                                            \
      _Pragma("unroll")                                                    \
      for (int n = 0; n < 4; ++n) {                                        \
        acc[m][n] = __builtin_amdgcn_mfma_f32_16x16x32_bf16(P##ah[m], P##bh[n], acc[m][n], 0, 0, 0); \
        acc[m][n] = __builtin_amdgcn_mfma_f32_16x16x32_bf16(P##ah[m], P##bl[n], acc[m][n], 0, 0, 0); \
        acc[m][n] = __builtin_amdgcn_mfma_f32_16x16x32_bf16(P##al[m], P##bh[n], acc[m][n], 0, 0, 0); \
      }                                                                    \
    PRIO(0);                                                               \
  } while (0)

  bf16x8 Aah[4], Aal[4], Abh[4], Abl[4];   // buffer A
  bf16x8 Bah[4], Bal[4], Bbh[4], Bbl[4];   // buffer B

  LOADF(A, 0);
  SB();
  for (int kt = 0; kt < 30; kt += 2) {
    LOADF(B, kt + 1);
    SB();
    FMAF(A);
    LOADF(A, kt + 2);
    SB();
    FMAF(B);
  }
  LOADF(B, 31);
  SB();
  FMAF(A);
  FMAF(B);

#undef LOADF
#undef FMAF

  const int rr = (lane >> 4) * 4;
  // direct tile write: S[brow..][bcol..]  (non-temporal: never re-read here)
#pragma unroll
  for (int m = 0; m < 4; ++m)
#pragma unroll
    for (int n = 0; n < 4; ++n)
#pragma unroll
      for (int r = 0; r < 4; ++r) {
        int row = brow + wr * 64 + m * 16 + rr + r;
        int col = bcol + wc * 64 + n * 16 + fr;
        __builtin_nontemporal_store(acc[m][n][r], &S[(size_t)row * N + col]);
      }

  // transposed tile write for off-diagonal blocks: S[bcol..][brow..]
  if (bi != bj) {
#pragma unroll
    for (int pass = 0; pass < 2; ++pass) {
      __syncthreads();
      if (wr == pass) {
#pragma unroll
        for (int m = 0; m < 4; ++m)
#pragma unroll
          for (int n = 0; n < 4; ++n) {
            f32x4 v = acc[m][n];
            int c = wc * 64 + n * 16 + fr;
            int inner = ((m * 16 + rr) * 4) ^ ((c & 15) << 4);
            *(f32x4*)((char*)&tbuf[c][0] + inner) = v;
          }
      }
      __syncthreads();
#pragma unroll
      for (int i = 0; i < 8; ++i) {
        int idx = i * 256 + tid;         // 2048 float4 = 128 cols x 16 quads
        int c = idx >> 4;
        int kq = idx & 15;
        int inner = (kq * 16) ^ ((c & 15) << 4);
        f32x4 v4 = *(const f32x4*)((const char*)&tbuf[c][0] + inner);
        __builtin_nontemporal_store(
            v4, (f32x4*)&S[(size_t)(bcol + c) * N + brow + pass * 64 + kq * 4]);
      }
    }
  }
}

// ---- K2: in-place row softmax (+ optional ROW-MAJOR bf16 P copy) -------
// NEW: nt load for S read, nt store for S write (S is dead after this
// kernel); Pb write stays cached so the 134 MB Pb survives in L3 for pv.
template <int WRITE_PB>
__global__ __launch_bounds__(256) void k_softmax(float* __restrict__ S,
                                                 u16* __restrict__ Pb) {
  const int row = blockIdx.x;
  float* p = S + (size_t)row * N;
  const int tid = threadIdx.x;
  const int wid = tid >> 6, lane = tid & 63;
  __shared__ float red[4];

  f32x4 v[8];
  float m = -INFINITY;
#pragma unroll
  for (int i = 0; i < 8; ++i) {
    int idx = i * 256 + tid;
    f32x4 x = __builtin_nontemporal_load((const f32x4*)p + idx);
    if ((row >> 2) == idx) x[row & 3] = -INFINITY;   // exclude diag
    v[i] = x;
    m = fmaxf(m, fmaxf(fmaxf(x[0], x[1]), fmaxf(x[2], x[3])));
  }
#pragma unroll
  for (int off = 32; off > 0; off >>= 1) m = fmaxf(m, __shfl_xor(m, off));
  if (lane == 0) red[wid] = m;
  __syncthreads();
  m = fmaxf(fmaxf(red[0], red[1]), fmaxf(red[2], red[3]));

  float s = 0.f;
#pragma unroll
  for (int i = 0; i < 8; ++i) {
    f32x4 e;
    e[0] = __expf(v[i][0] - m);
    e[1] = __expf(v[i][1] - m);
    e[2] = __expf(v[i][2] - m);
    e[3] = __expf(v[i][3] - m);
    v[i] = e;
    s += e[0] + e[1] + e[2] + e[3];
  }
#pragma unroll
  for (int off = 32; off > 0; off >>= 1) s += __shfl_xor(s, off);
  __syncthreads();
  if (lane == 0) red[wid] = s;
  __syncthreads();
  s = red[0] + red[1] + red[2] + red[3];
  float inv = 1.0f / s;
#pragma unroll
  for (int i = 0; i < 8; ++i) {
    int idx = i * 256 + tid;
    f32x4 x = v[i];
    x[0] *= inv; x[1] *= inv; x[2] *= inv; x[3] *= inv;
    __builtin_nontemporal_store(x, (f32x4*)p + idx);
    if (WRITE_PB) {
      ushort4 h = {f2bf(x[0]), f2bf(x[1]), f2bf(x[2]), f2bf(x[3])};
      ((ushort4*)(Pb + (size_t)row * N))[idx] = h;   // cached: pv re-reads
    }
  }
}

// -------- K3: out = P @ X. BM=128, BN=256, 512 thr, deep pipeline -------
// (R13-proven best pv.) A: Pb via gload_lds into As[4]; B: asm-pinned
// B0/B1/B2 from XTf. 5 vmem/step/wave -> WAITV(10) steady. nt Out stores.
__global__ __launch_bounds__(512) void k_pv(const u16* __restrict__ Pb,
                                            const u16* __restrict__ XTf,
                                            float* __restrict__ Out) {
  __shared__ u16 As[4][128 * 32];   // 32 KiB
  const int tid = threadIdx.x, wid = tid >> 6, lane = tid & 63;

  // XCD chunk swizzle over 256 blocks (q=32, bijective)
  int o = blockIdx.x;
  int l = (o & 7) * 32 + (o >> 3);
  const int brow = (l >> 2) * 128;
  const int bcol = (l & 3) * 256;

  const int wr = wid >> 2, wc = wid & 3;   // 2x4 waves, 64x64 each
  const int fr = lane & 15;
  const int c0 = lane >> 4;

  const char* pB = (const char*)XTf + (size_t)(bcol / 16 + wc * 4) * 1024 + lane * 16;

  f32x4 acc[4][4] = {};

#define STAGEA(t) do {                                                     \
    int ebyte = wid * 1024 + lane * 16;                                    \
    int row = ebyte >> 6;                                                  \
    int pc = (ebyte >> 4) & 3;                                             \
    int col = (pc ^ ((row >> 1) & 3)) * 8;                                 \
    gload_lds16(Pb + (size_t)(brow + row) * N + (size_t)(t) * 32 + col,    \
                (const char*)As[(t) & 3] + ebyte);                         \
  } while (0)

#define LOADB(BUF, t) do {                                                 \
    const char* b_ = pB + ((size_t)(t) << 16);                             \
    ALOAD(BUF[0], b_);                                                     \
    ALOAD(BUF[1], b_ + 1024);                                              \
    ALOAD(BUF[2], b_ + 2048);                                              \
    ALOAD(BUF[3], b_ + 3072);                                              \
  } while (0)

#define PV_COMPUTE(s, BUF) do {                                            \
    bf16x8 a[4];                                                           \
    _Pragma("unroll")                                                      \
    for (int m = 0; m < 4; ++m) {                                          \
      int row = wr * 64 + m * 16 + fr;                                     \
      a[m] = *(const bf16x8*)((const char*)As[s] + swz_byte(row, c0));     \
    }                                                                      \
    PRIO(1);                                                               \
    _Pragma("unroll")                                                      \
    for (int m = 0; m < 4; ++m)                                            \
      _Pragma("unroll")                                                    \
      for (int n = 0; n < 4; ++n)                                          \
        acc[m][n] = __builtin_amdgcn_mfma_f32_16x16x32_bf16(a[m], BUF[n], acc[m][n], 0, 0, 0); \
    PRIO(0);                                                               \
  } while (0)

// One steady-state step: retire tile `it`'s 5 loads (10 newer stay in
// flight), compute it, then issue tile it+3 into the just-freed B buffer.
#define STEP(it, BUF) do {                                                 \
    WAITV(10);                                                             \
    SB();                                                                  \
    BAR();                                                                 \
    PV_COMPUTE((it) & 3, BUF);                                             \
    BAR();                                                                 \
    STAGEA((it) + 3);                                                      \
    LOADB(BUF, (it) + 3);                                                  \
    SB();                                                                  \
  } while (0)

  bf16x8 B0[4], B1[4], B2[4];   // asm-pinned rotation buffers

  STAGEA(0); LOADB(B0, 0);
  STAGEA(1); LOADB(B1, 1);
  STAGEA(2); LOADB(B2, 2);      // 15 loads/wave outstanding
  SB();

  for (int t = 0; t < 84; ++t) {   // it = 3t .. 3t+2, covers 0..251
    int it = t * 3;
    STEP(it, B0);
    STEP(it + 1, B1);
    STEP(it + 2, B2);
  }
  STEP(252, B0);                 // issues tile 255 into B0
  // tail: no more issues; drain 10 -> 5 -> 0
  WAITV(10); SB(); BAR();
  PV_COMPUTE(253 & 3, B1);
  BAR();
  WAITV(5); SB(); BAR();
  PV_COMPUTE(254 & 3, B2);
  BAR();
  WAITV(0); SB(); BAR();
  PV_COMPUTE(255 & 3, B0);

#undef STEP
#undef STAGEA
#undef LOADB
#undef PV_COMPUTE

  const int rr = (lane >> 4) * 4;
#pragma unroll
  for (int m = 0; m < 4; ++m)
#pragma unroll
    for (int n = 0; n < 4; ++n)
#pragma unroll
      for (int r = 0; r < 4; ++r) {
        int row = brow + wr * 64 + m * 16 + rr + r;
        int col = bcol + wc * 64 + n * 16 + fr;
        __builtin_nontemporal_store(acc[m][n][r], &Out[(size_t)row * D + col]);
      }
}

// -------- K3 fallback: out = P @ X from fp32 P (row-major XT) -----------
__global__ __launch_bounds__(512) void k_pv_f32(const float* __restrict__ P,
                                                const u16* __restrict__ XT,
                                                float* __restrict__ Out) {
  __shared__ u16 As[128 * 32];
  __shared__ u16 Bs[256 * 32];
  const int tid = threadIdx.x, wid = tid >> 6, lane = tid & 63;
  const int brow = blockIdx.y * 128;
  const int bcol = blockIdx.x * 256;
  const int wr = wid >> 2, wc = wid & 3;
  const int fr = lane & 15;
  const int c0 = lane >> 4;

  f32x4 acc[4][4] = {};

  for (int kt = 0; kt < N; kt += 32) {
    __syncthreads();
#pragma unroll
    for (int c = 0; c < 2; ++c) {
      int chunk = wid * 2 + c;
      int ebyte = chunk * 1024 + lane * 16;
      int row = ebyte >> 6;
      int pc = (ebyte >> 4) & 3;
      int col = (pc ^ ((row >> 1) & 3)) * 8;
      gload_lds16(XT + (size_t)(bcol + row) * N + kt + col, (const char*)Bs + ebyte);
    }
#pragma unroll
    for (int i = 0; i < 2; ++i) {
      int idx = i * 512 + tid;
      int e = idx * 4;
      int row = e >> 5, col = e & 31;
      float4 x = *(const float4*)(P + (size_t)(brow + row) * N + kt + col);
      ushort4 h = {f2bf(x.x), f2bf(x.y), f2bf(x.z), f2bf(x.w)};
      int inner = (col * 2) ^ (((row >> 1) & 3) << 4);
      *(ushort4*)((char*)As + row * 64 + inner) = h;
    }
    __syncthreads();

    bf16x8 a[4], b[4];
#pragma unroll
    for (int m = 0; m < 4; ++m) {
      int row = wr * 64 + m * 16 + fr;
      a[m] = *(const bf16x8*)((const char*)As + swz_byte(row, c0));
    }
#pragma unroll
    for (int n = 0; n < 4; ++n) {
      int row = wc * 64 + n * 16 + fr;
      b[n] = *(const bf16x8*)((const char*)Bs + swz_byte(row, c0));
    }
#pragma unroll
    for (int m = 0; m < 4; ++m)
#pragma unroll
      for (int n = 0; n < 4; ++n)
        acc[m][n] = __builtin_amdgcn_mfma_f32_16x16x32_bf16(a[m], b[n], acc[m][n], 0, 0, 0);
  }

  const int rr = (lane >> 4) * 4;
#pragma unroll
  for (int m = 0; m < 4; ++m)
#pragma unroll
    for (int n = 0; n < 4; ++n)
#pragma unroll
      for (int r = 0; r < 4; ++r) {
        int row = brow + wr * 64 + m * 16 + rr + r;
        int col = bcol + wc * 64 + n * 16 + fr;
        Out[(size_t)row * D + col] = acc[m][n][r];
      }
}

extern "C" void kernel_launch(void* const* d_in, const int* in_sizes, int n_in,
                              void* d_out, int out_size, void* d_ws, size_t ws_size,
                              hipStream_t stream) {
  const float* X = (const float*)d_in[0];
  float* out = (float*)d_out;
  float* attn = out + (size_t)N * D;        // second output: raw S, then softmaxed

  u16* Xf = (u16*)d_ws;                     // 32 MB (frag-major hi|lo)
  u16* XT = Xf + (size_t)2 * N * D;         // 16 MB (XTf frag-major, or row-major)
  u16* Pb = XT + (size_t)N * D;             // 128 MB (row-major, optional)
  const bool usePb =
      ws_size >= ((size_t)N * D * 3 + (size_t)N * N) * sizeof(u16);

  k_split<<<(N * D / 8) / 256, 256, 0, stream>>>(X, Xf);
  k_qkt<<<64 * 65 / 2, 256, 0, stream>>>(Xf, attn);
  if (usePb) {
    k_xt<1><<<dim3(D / 32, N / 32), 256, 0, stream>>>(X, XT);
    k_softmax<1><<<N, 256, 0, stream>>>(attn, Pb);
    k_pv<<<256, 512, 0, stream>>>(Pb, XT, out);
  } else {
    k_xt<0><<<dim3(D / 32, N / 32), 256, 0, stream>>>(X, XT);
    k_softmax<0><<<N, 256, 0, stream>>>(attn, nullptr);
    k_pv_f32<<<dim3(D / 256, N / 128), 512, 0, stream>>>(attn, XT, out);
  }
}